// Round 6
// baseline (859.634 us; speedup 1.0000x reference)
//
#include <hip/hip_runtime.h>
#include <stdint.h>

#define B_TOT 131072
#define GAP_TAU 2.5e-4f

typedef short v8s __attribute__((ext_vector_type(8)));
typedef float v4f __attribute__((ext_vector_type(4)));

__device__ __forceinline__ unsigned short f2bf(float f) {
    union { float f; unsigned u; } v; v.f = f;
    unsigned u = v.u;
    u += 0x7fffu + ((u >> 16) & 1u);      // RNE
    return (unsigned short)(u >> 16);
}
__device__ __forceinline__ float bf2f(unsigned short s) {
    union { unsigned u; float f; } v; v.u = ((unsigned)s) << 16;
    return v.f;
}
__device__ __forceinline__ unsigned pack2(float lo, float hi) {
    return (unsigned)f2bf(lo) | ((unsigned)f2bf(hi) << 16);
}

// ---------------- K0: prep ----------------
__global__ void k_prep(const float* __restrict__ W_dh,
                       const float* __restrict__ b_do,
                       const float* __restrict__ dec_b,
                       const float* __restrict__ pre_bias,
                       const float* __restrict__ W_do,
                       const float* __restrict__ W_eh,
                       const float* __restrict__ W_eo,
                       float* __restrict__ WdhT,
                       float* __restrict__ bias3,
                       unsigned short* __restrict__ Wdo_frag,
                       unsigned short* __restrict__ WehHi,
                       unsigned short* __restrict__ WehLo,
                       unsigned short* __restrict__ WeoHi,
                       unsigned short* __restrict__ WeoLo,
                       float* __restrict__ spars_out)
{
    int t = blockIdx.x * blockDim.x + threadIdx.x;
    int nthr = gridDim.x * blockDim.x;
    for (int i = t; i < 512 * 64; i += nthr) {
        int h = i >> 6, l = i & 63;
        WdhT[l * 512 + h] = W_dh[i];
    }
    // Wdo_frag (B-operand layout for k_dec), plain bf16
    for (int g = t; g < 16384; g += nthr) {
        int lane = g & 63;
        int q = g >> 6;
        int nt = q >> 4, kc = q & 15;
        int col = nt * 16 + (lane & 15);
        int kbase = kc * 32 + (lane >> 4) * 8;
        const float* src = &W_do[(size_t)col * 512 + kbase];
        unsigned short* dst = &Wdo_frag[(size_t)g * 8];
        #pragma unroll
        for (int i = 0; i < 8; i++) dst[i] = f2bf(src[i]);
    }
    // W_eh hi/lo frags: 32 ct x 8 kcg x 64 lanes
    for (int g = t; g < 32 * 8 * 64; g += nthr) {
        int lane = g & 63;
        int rem = g >> 6;
        int kcg = rem & 7, ct = rem >> 3;
        int c = ct * 16 + (lane & 15);
        int k = kcg * 32 + (lane >> 4) * 8;
        const float* src = &W_eh[(size_t)c * 256 + k];
        #pragma unroll
        for (int i = 0; i < 8; i++) {
            unsigned short hi = f2bf(src[i]);
            WehHi[(size_t)g * 8 + i] = hi;
            WehLo[(size_t)g * 8 + i] = f2bf(src[i] - bf2f(hi));
        }
    }
    // W_eo hi/lo frags: 4 lt x 16 kcg x 64 lanes
    for (int g = t; g < 4 * 16 * 64; g += nthr) {
        int lane = g & 63;
        int rem = g >> 6;
        int kcg = rem & 15, lt = rem >> 4;
        int l = lt * 16 + (lane & 15);
        int k = kcg * 32 + (lane >> 4) * 8;
        const float* src = &W_eo[(size_t)l * 512 + k];
        #pragma unroll
        for (int i = 0; i < 8; i++) {
            unsigned short hi = f2bf(src[i]);
            WeoHi[(size_t)g * 8 + i] = hi;
            WeoLo[(size_t)g * 8 + i] = f2bf(src[i] - bf2f(hi));
        }
    }
    if (t < 256) bias3[t] = b_do[t] + dec_b[t] + pre_bias[t];
    if (t == 0) spars_out[0] = 5.0f / 64.0f;
}

// ---------------- K1: h = relu((x-pre_bias) @ W_eh^T + b_eh), split-bf16 MFMA ----------------
// Restructured: stage full x tile ONCE (swizzled hi/lo bf16 LDS), one barrier, then a
// fully-unrolled barrier-free MFMA loop (compiler free to pipeline W loads across chunks).
__global__ __launch_bounds__(256, 2)
void k_enc1(const float* __restrict__ x,        // chunk-local [rows][256]
            const float* __restrict__ pre_bias,
            const unsigned short* __restrict__ WehHi,
            const unsigned short* __restrict__ WehLo,
            const float* __restrict__ b_eh,
            unsigned short* __restrict__ hHi,   // chunk-local [rows][512]
            unsigned short* __restrict__ hLo,
            int* __restrict__ fcount)
{
    if (blockIdx.x == 0 && blockIdx.y == 0 && threadIdx.x == 0) *fcount = 0;
    __shared__ __align__(16) unsigned short xH[64 * 256];  // 32 KB, [row][k] swizzled
    __shared__ __align__(16) unsigned short xL[64 * 256];  // 32 KB
    const int t    = threadIdx.x;
    const int lane = t & 63;
    const int w    = t >> 6;
    const int rb   = blockIdx.x * 64;
    const int cb   = blockIdx.y * 256;

    // ---- stage x tile (64 r x 256 k) as swizzled hi/lo bf16 ----
    {
        const int r  = t >> 2;          // 0..63
        const int kq = (t & 3) * 64;    // col span
        const float* xr = &x[(size_t)(rb + r) * 256 + kq];
        const float* pb = &pre_bias[kq];
        char* bh = (char*)xH + r * 512;
        char* bl = (char*)xL + r * 512;
        const int sw = (r & 7) << 4;
        #pragma unroll
        for (int p = 0; p < 8; p++) {
            const float4 v0 = *reinterpret_cast<const float4*>(&xr[p * 8]);
            const float4 v1 = *reinterpret_cast<const float4*>(&xr[p * 8 + 4]);
            const float4 p0 = *reinterpret_cast<const float4*>(&pb[p * 8]);
            const float4 p1 = *reinterpret_cast<const float4*>(&pb[p * 8 + 4]);
            float f[8] = {v0.x - p0.x, v0.y - p0.y, v0.z - p0.z, v0.w - p0.w,
                          v1.x - p1.x, v1.y - p1.y, v1.z - p1.z, v1.w - p1.w};
            unsigned hi2[4], lo2[4];
            #pragma unroll
            for (int q = 0; q < 4; q++) {
                unsigned short h0 = f2bf(f[q * 2]), h1 = f2bf(f[q * 2 + 1]);
                hi2[q] = (unsigned)h0 | ((unsigned)h1 << 16);
                lo2[q] = (unsigned)f2bf(f[q * 2] - bf2f(h0)) | ((unsigned)f2bf(f[q * 2 + 1] - bf2f(h1)) << 16);
            }
            const int kb = (kq + p * 8) * 2;    // byte offset in row
            *reinterpret_cast<uint4*>(bh + (kb ^ sw)) = *reinterpret_cast<uint4*>(hi2);
            *reinterpret_cast<uint4*>(bl + (kb ^ sw)) = *reinterpret_cast<uint4*>(lo2);
        }
    }
    __syncthreads();

    v4f acc[4][4];
    #pragma unroll
    for (int i = 0; i < 4; i++)
        #pragma unroll
        for (int j = 0; j < 4; j++) acc[i][j] = (v4f){0.f, 0.f, 0.f, 0.f};

    // ---- barrier-free MFMA loop, fully unrolled ----
    #pragma unroll
    for (int kc = 0; kc < 8; ++kc) {
        v8s wh[4], wl[4];
        #pragma unroll
        for (int ntl = 0; ntl < 4; ntl++) {
            const int ct = (cb >> 4) + w * 4 + ntl;
            const size_t idx = ((size_t)(ct * 8 + kc) * 64 + lane) * 8;
            wh[ntl] = *reinterpret_cast<const v8s*>(&WehHi[idx]);
            wl[ntl] = *reinterpret_cast<const v8s*>(&WehLo[idx]);
        }
        v8s ah[4], al[4];
        #pragma unroll
        for (int mt = 0; mt < 4; mt++) {
            const int row = mt * 16 + (lane & 15);
            const int boff = row * 512 + ((kc * 64 + (lane >> 4) * 16) ^ ((row & 7) << 4));
            ah[mt] = *reinterpret_cast<const v8s*>((char*)xH + boff);
            al[mt] = *reinterpret_cast<const v8s*>((char*)xL + boff);
        }
        #pragma unroll
        for (int mt = 0; mt < 4; mt++) {
            #pragma unroll
            for (int ntl = 0; ntl < 4; ntl++) {
                acc[mt][ntl] = __builtin_amdgcn_mfma_f32_16x16x32_bf16(wh[ntl], ah[mt], acc[mt][ntl], 0, 0, 0);
                acc[mt][ntl] = __builtin_amdgcn_mfma_f32_16x16x32_bf16(wl[ntl], ah[mt], acc[mt][ntl], 0, 0, 0);
                acc[mt][ntl] = __builtin_amdgcn_mfma_f32_16x16x32_bf16(wh[ntl], al[mt], acc[mt][ntl], 0, 0, 0);
            }
        }
    }
    // ---- epilogue: relu(acc + b_eh) -> hi/lo planes (4 consecutive cols per lane) ----
    #pragma unroll
    for (int mt = 0; mt < 4; mt++) {
        const size_t r = (size_t)(rb + mt * 16 + (lane & 15));
        #pragma unroll
        for (int ntl = 0; ntl < 4; ntl++) {
            const int c = cb + w * 64 + ntl * 16 + (lane >> 4) * 4;
            const float4 be = *reinterpret_cast<const float4*>(&b_eh[c]);
            float h0 = fmaxf(acc[mt][ntl][0] + be.x, 0.f);
            float h1 = fmaxf(acc[mt][ntl][1] + be.y, 0.f);
            float h2 = fmaxf(acc[mt][ntl][2] + be.z, 0.f);
            float h3 = fmaxf(acc[mt][ntl][3] + be.w, 0.f);
            unsigned short s0 = f2bf(h0), s1 = f2bf(h1), s2 = f2bf(h2), s3 = f2bf(h3);
            uint2 phi = { (unsigned)s0 | ((unsigned)s1 << 16), (unsigned)s2 | ((unsigned)s3 << 16) };
            uint2 plo = { (unsigned)f2bf(h0 - bf2f(s0)) | ((unsigned)f2bf(h1 - bf2f(s1)) << 16),
                          (unsigned)f2bf(h2 - bf2f(s2)) | ((unsigned)f2bf(h3 - bf2f(s3)) << 16) };
            *reinterpret_cast<uint2*>(&hHi[r * 512 + c]) = phi;
            *reinterpret_cast<uint2*>(&hLo[r * 512 + c]) = plo;
        }
    }
}

// ---------------- K2: pre_act (split-bf16 MFMA); top-5; gap-flag; outputs ----------------
__global__ __launch_bounds__(256, 4)
void k_enc2_topk(const unsigned short* __restrict__ hHi,
                 const unsigned short* __restrict__ hLo,
                 const unsigned short* __restrict__ WeoHi,
                 const unsigned short* __restrict__ WeoLo,
                 const float* __restrict__ b_eo,
                 const float* __restrict__ lat_b,
                 float* __restrict__ pre_out,
                 float* __restrict__ mask_out,
                 float* __restrict__ sl_out,
                 float* __restrict__ t5v,          // chunk-local [cap][5]
                 int*   __restrict__ t5i,
                 int*   __restrict__ fcount,
                 int*   __restrict__ flist,
                 int row0)
{
    __shared__ float pa[64][68];
    __shared__ unsigned long long mbits[64];
    const int t    = threadIdx.x;
    const int lane = t & 63;
    const int w    = t >> 6;
    const int rb   = blockIdx.x * 64;

    v4f acc[4];
    #pragma unroll
    for (int i = 0; i < 4; i++) acc[i] = (v4f){0.f, 0.f, 0.f, 0.f};

    #pragma unroll 1
    for (int kcl = 0; kcl < 16; ++kcl) {
        const size_t hoff = (size_t)(rb + w * 16 + (lane & 15)) * 512 + kcl * 32 + (lane >> 4) * 8;
        const v8s hh = *reinterpret_cast<const v8s*>(&hHi[hoff]);
        const v8s hl = *reinterpret_cast<const v8s*>(&hLo[hoff]);
        #pragma unroll
        for (int lt = 0; lt < 4; lt++) {
            const size_t idx = ((size_t)(lt * 16 + kcl) * 64 + lane) * 8;
            const v8s wh = *reinterpret_cast<const v8s*>(&WeoHi[idx]);
            const v8s wl = *reinterpret_cast<const v8s*>(&WeoLo[idx]);
            acc[lt] = __builtin_amdgcn_mfma_f32_16x16x32_bf16(wh, hh, acc[lt], 0, 0, 0);
            acc[lt] = __builtin_amdgcn_mfma_f32_16x16x32_bf16(wl, hh, acc[lt], 0, 0, 0);
            acc[lt] = __builtin_amdgcn_mfma_f32_16x16x32_bf16(wh, hl, acc[lt], 0, 0, 0);
        }
    }
    #pragma unroll
    for (int lt = 0; lt < 4; lt++) {
        const int l0 = lt * 16 + ((lane >> 4) << 2);
        const float4 be = *reinterpret_cast<const float4*>(&b_eo[l0]);
        const float4 lb = *reinterpret_cast<const float4*>(&lat_b[l0]);
        float4 o;
        o.x = acc[lt][0] + be.x + lb.x;
        o.y = acc[lt][1] + be.y + lb.y;
        o.z = acc[lt][2] + be.z + lb.z;
        o.w = acc[lt][3] + be.w + lb.w;
        *reinterpret_cast<float4*>(&pa[w * 16 + (lane & 15)][l0]) = o;
    }
    __syncthreads();
    // top-5 + 6th for gap check (threads 0..63)
    if (t < 64) {
        int r = t;
        unsigned long long used = 0ULL;
        float bv[5]; int bi[5];
        #pragma unroll
        for (int p = 0; p < 5; p++) {
            float best = -3.402823466e38f; int bidx = 0;
            for (int j = 0; j < 64; j++) {
                float v = pa[r][j];
                if (!((used >> j) & 1ULL) && v > best) { best = v; bidx = j; }
            }
            used |= 1ULL << bidx;
            bv[p] = best; bi[p] = bidx;
        }
        mbits[r] = used;
        size_t lr = (size_t)(rb + r);
        #pragma unroll
        for (int p = 0; p < 5; p++) { t5v[lr * 5 + p] = bv[p]; t5i[lr * 5 + p] = bi[p]; }
        // 6th max
        float v6 = -3.402823466e38f;
        for (int j = 0; j < 64; j++) {
            float v = pa[r][j];
            if (!((used >> j) & 1ULL) && v > v6) v6 = v;
        }
        if (bv[4] - v6 < GAP_TAU) {
            int slot = atomicAdd(fcount, 1);
            flist[slot] = rb + r;
        }
    }
    __syncthreads();
    {
        int row = t >> 2, c0 = (t & 3) * 16;
        size_t gr = (size_t)(row0 + rb + row);
        unsigned long long bits = mbits[row];
        #pragma unroll
        for (int g = 0; g < 4; g++) {
            int c = c0 + g * 4;
            float p0 = pa[row][c + 0], p1 = pa[row][c + 1], p2 = pa[row][c + 2], p3 = pa[row][c + 3];
            float m0 = (float)((bits >> (c + 0)) & 1ULL);
            float m1 = (float)((bits >> (c + 1)) & 1ULL);
            float m2 = (float)((bits >> (c + 2)) & 1ULL);
            float m3 = (float)((bits >> (c + 3)) & 1ULL);
            float4 pv = {p0, p1, p2, p3};
            float4 mv = {m0, m1, m2, m3};
            float4 sv = {m0 * p0, m1 * p1, m2 * p2, m3 * p3};
            *reinterpret_cast<float4*>(&pre_out[gr * 64 + c])  = pv;
            *reinterpret_cast<float4*>(&mask_out[gr * 64 + c]) = mv;
            *reinterpret_cast<float4*>(&sl_out[gr * 64 + c])   = sv;
        }
    }
}

// ---------------- K2b: fp32 exact repair of gap-flagged rows ----------------
__global__ __launch_bounds__(256)
void k_repair(const float* __restrict__ x,        // chunk-local
              const float* __restrict__ pre_bias,
              const float* __restrict__ W_eh,     // [512][256]
              const float* __restrict__ b_eh,
              const float* __restrict__ W_eo,     // [64][512]
              const float* __restrict__ b_eo,
              const float* __restrict__ lat_b,
              const int* __restrict__ fcount,
              const int* __restrict__ flist,
              float* __restrict__ pre_out,
              float* __restrict__ mask_out,
              float* __restrict__ sl_out,
              float* __restrict__ t5v,            // chunk-local
              int*   __restrict__ t5i,
              int row0)
{
    __shared__ float xs[256];
    __shared__ float hs[512];
    __shared__ float part[64][4];
    __shared__ float pav[64];
    __shared__ unsigned long long bitsS;
    const int t = threadIdx.x;
    const int n = *fcount;
    #pragma unroll 1
    for (int it = blockIdx.x; it < n; it += gridDim.x) {
        const int r = flist[it];
        xs[t] = x[(size_t)r * 256 + t] - pre_bias[t];
        __syncthreads();
        #pragma unroll 1
        for (int j = t; j < 512; j += 256) {
            const float* wr = &W_eh[(size_t)j * 256];
            float acc = 0.f;
            #pragma unroll
            for (int k = 0; k < 256; k += 4) {
                const float4 wv = *reinterpret_cast<const float4*>(&wr[k]);
                acc = fmaf(wv.x, xs[k + 0], acc);
                acc = fmaf(wv.y, xs[k + 1], acc);
                acc = fmaf(wv.z, xs[k + 2], acc);
                acc = fmaf(wv.w, xs[k + 3], acc);
            }
            hs[j] = fmaxf(acc + b_eh[j], 0.f);
        }
        __syncthreads();
        {
            const int l = t & 63, q = t >> 6;
            const float* wr = &W_eo[(size_t)l * 512 + q * 128];
            const float* hp = &hs[q * 128];
            float acc = 0.f;
            #pragma unroll
            for (int k = 0; k < 128; k += 4) {
                const float4 wv = *reinterpret_cast<const float4*>(&wr[k]);
                acc = fmaf(wv.x, hp[k + 0], acc);
                acc = fmaf(wv.y, hp[k + 1], acc);
                acc = fmaf(wv.z, hp[k + 2], acc);
                acc = fmaf(wv.w, hp[k + 3], acc);
            }
            part[l][q] = acc;
        }
        __syncthreads();
        if (t < 64)
            pav[t] = ((part[t][0] + part[t][1]) + (part[t][2] + part[t][3])) + b_eo[t] + lat_b[t];
        __syncthreads();
        if (t == 0) {
            unsigned long long used = 0ULL;
            const size_t lr = (size_t)r;
            #pragma unroll
            for (int p = 0; p < 5; p++) {
                float best = -3.402823466e38f; int bidx = 0;
                for (int j = 0; j < 64; j++) {
                    float v = pav[j];
                    if (!((used >> j) & 1ULL) && v > best) { best = v; bidx = j; }
                }
                used |= 1ULL << bidx;
                t5v[lr * 5 + p] = best; t5i[lr * 5 + p] = bidx;
            }
            bitsS = used;
        }
        __syncthreads();
        if (t < 64) {
            const size_t gr = (size_t)(row0 + r);
            const float v = pav[t];
            const float m = (float)((bitsS >> t) & 1ULL);
            pre_out[gr * 64 + t]  = v;
            mask_out[gr * 64 + t] = m;
            sl_out[gr * 64 + t]   = m * v;
        }
        __syncthreads();
    }
}

// ---------------- K3: recon via bf16 MFMA (unchanged, validated) ----------------
__global__ __launch_bounds__(256)
void k_dec(const float* __restrict__ t5v, const int* __restrict__ t5i,   // chunk-local
           const float* __restrict__ WdhT,        // [64][512] fp32
           const float* __restrict__ b_dh,
           const unsigned short* __restrict__ Wdo_frag,
           const float* __restrict__ bias3,
           float* __restrict__ recon,             // global [B][256]
           int row0)
{
    __shared__ __align__(16) short sA[64 * 136];
    __shared__ float svv[64][5];
    __shared__ int   sii[64][5];
    const int t    = threadIdx.x;
    const int rb   = blockIdx.x * 64;
    const int lane = t & 63;
    const int w    = t >> 6;
    const int r    = t & 63;

    for (int i = t; i < 320; i += 256) {
        int rr = i / 5, p = i % 5;
        size_t lr = (size_t)(rb + rr);
        svv[rr][p] = t5v[lr * 5 + p];
        sii[rr][p] = t5i[lr * 5 + p];
    }
    __syncthreads();

    v4f acc[4][4];
    #pragma unroll
    for (int i = 0; i < 4; i++)
        #pragma unroll
        for (int j = 0; j < 4; j++) acc[i][j] = (v4f){0.f, 0.f, 0.f, 0.f};

    #pragma unroll 1
    for (int c = 0; c < 4; ++c) {
        const int k0 = c * 128;
        {
            const int kbase = k0 + w * 32;
            float a[32];
            #pragma unroll
            for (int q = 0; q < 8; q++) {
                const float4 bd = *reinterpret_cast<const float4*>(&b_dh[kbase + q * 4]);
                a[q * 4 + 0] = bd.x; a[q * 4 + 1] = bd.y; a[q * 4 + 2] = bd.z; a[q * 4 + 3] = bd.w;
            }
            #pragma unroll
            for (int p = 0; p < 5; p++) {
                const float s = svv[r][p];
                const float4* wp = reinterpret_cast<const float4*>(&WdhT[(size_t)sii[r][p] * 512 + kbase]);
                #pragma unroll
                for (int q = 0; q < 8; q++) {
                    const float4 wv = wp[q];
                    a[q * 4 + 0] = fmaf(s, wv.x, a[q * 4 + 0]);
                    a[q * 4 + 1] = fmaf(s, wv.y, a[q * 4 + 1]);
                    a[q * 4 + 2] = fmaf(s, wv.z, a[q * 4 + 2]);
                    a[q * 4 + 3] = fmaf(s, wv.w, a[q * 4 + 3]);
                }
            }
            char* base = (char*)sA + r * 272 + w * 64;
            #pragma unroll
            for (int q2 = 0; q2 < 4; q2++) {
                uint4 o;
                o.x = pack2(fmaxf(a[q2 * 8 + 0], 0.f), fmaxf(a[q2 * 8 + 1], 0.f));
                o.y = pack2(fmaxf(a[q2 * 8 + 2], 0.f), fmaxf(a[q2 * 8 + 3], 0.f));
                o.z = pack2(fmaxf(a[q2 * 8 + 4], 0.f), fmaxf(a[q2 * 8 + 5], 0.f));
                o.w = pack2(fmaxf(a[q2 * 8 + 6], 0.f), fmaxf(a[q2 * 8 + 7], 0.f));
                *reinterpret_cast<uint4*>(base + q2 * 16) = o;
            }
        }
        __syncthreads();
        #pragma unroll
        for (int kcl = 0; kcl < 4; ++kcl) {
            const int kcg = c * 4 + kcl;
            v8s af[4];
            #pragma unroll
            for (int mt = 0; mt < 4; mt++)
                af[mt] = *reinterpret_cast<const v8s*>(
                    (char*)sA + (mt * 16 + (lane & 15)) * 272 + kcl * 64 + (lane >> 4) * 16);
            v8s bf[4];
            #pragma unroll
            for (int ntl = 0; ntl < 4; ntl++) {
                const int ntg = w * 4 + ntl;
                bf[ntl] = *reinterpret_cast<const v8s*>(
                    Wdo_frag + ((size_t)(ntg * 16 + kcg) * 64 + lane) * 8);
            }
            #pragma unroll
            for (int mt = 0; mt < 4; mt++)
                #pragma unroll
                for (int ntl = 0; ntl < 4; ntl++)
                    acc[mt][ntl] = __builtin_amdgcn_mfma_f32_16x16x32_bf16(
                        af[mt], bf[ntl], acc[mt][ntl], 0, 0, 0);
        }
        __syncthreads();
    }
    #pragma unroll
    for (int ntl = 0; ntl < 4; ntl++) {
        const int col = w * 64 + ntl * 16 + (lane & 15);
        const float bz = bias3[col];
        #pragma unroll
        for (int mt = 0; mt < 4; mt++) {
            #pragma unroll
            for (int j = 0; j < 4; j++) {
                const size_t row = (size_t)(row0 + rb + mt * 16 + (lane >> 4) * 4 + j);
                recon[row * 256 + col] = acc[mt][ntl][j] + bz;
            }
        }
    }
}

// ---------------- host ----------------
extern "C" void kernel_launch(void* const* d_in, const int* in_sizes, int n_in,
                              void* d_out, int out_size, void* d_ws, size_t ws_size,
                              hipStream_t stream)
{
    const float* x        = (const float*)d_in[0];
    const float* pre_bias = (const float*)d_in[1];
    const float* W_eh     = (const float*)d_in[2];
    const float* b_eh     = (const float*)d_in[3];
    const float* W_eo     = (const float*)d_in[4];
    const float* b_eo     = (const float*)d_in[5];
    const float* lat_b    = (const float*)d_in[6];
    const float* W_dh     = (const float*)d_in[7];
    const float* b_dh     = (const float*)d_in[8];
    const float* W_do     = (const float*)d_in[9];
    const float* b_do     = (const float*)d_in[10];
    const float* dec_b    = (const float*)d_in[11];

    float* out = (float*)d_out;
    float* recon_out = out;
    float* sl_out    = out + (size_t)B_TOT * 256;
    float* pre_out   = sl_out + (size_t)B_TOT * 64;
    float* mask_out  = pre_out + (size_t)B_TOT * 64;
    float* spars_out = mask_out + (size_t)B_TOT * 64;

    // ws: WdhT 128K | bias3 1K | WdoF 256K | WehHi 256K | WehLo 256K | WeoHi 64K | WeoLo 64K
    //     | fcount 64B | flist cap*4 | t5v cap*20 | t5i cap*20 | hHi cap*1024 | hLo cap*1024
    char* ws = (char*)d_ws;
    float* WdhT           = (float*)ws;
    float* bias3          = (float*)(ws + 131072);
    unsigned short* WdoF  = (unsigned short*)(ws + 132096);
    unsigned short* WehHi = (unsigned short*)(ws + 394240);
    unsigned short* WehLo = (unsigned short*)(ws + 656384);
    unsigned short* WeoHi = (unsigned short*)(ws + 918528);
    unsigned short* WeoLo = (unsigned short*)(ws + 984064);
    int* fcount           = (int*)(ws + 1049600);
    const size_t base = 1049664;

    size_t avail = ws_size > base ? ws_size - base : 0;
    long long cap = (long long)(avail / 2092);    // flist 4 + t5 40 + h planes 2048 per row
    cap &= ~63LL;
    if (cap < 64) cap = 64;
    if (cap > 32768) cap = 32768;     // keep h planes (67 MB) L3-resident
    if (cap > B_TOT) cap = B_TOT;

    int*   flist = (int*)  (ws + base);
    float* t5v   = (float*)(ws + base + (size_t)cap * 4);
    int*   t5i   = (int*)  (ws + base + (size_t)cap * 24);
    unsigned short* hHi = (unsigned short*)(ws + base + (size_t)cap * 44);
    unsigned short* hLo = hHi + (size_t)cap * 512;

    k_prep<<<32, 256, 0, stream>>>(W_dh, b_do, dec_b, pre_bias, W_do, W_eh, W_eo,
                                   WdhT, bias3, WdoF, WehHi, WehLo, WeoHi, WeoLo, spars_out);

    for (int r0 = 0; r0 < B_TOT; r0 += (int)cap) {
        int rows = B_TOT - r0 < (int)cap ? B_TOT - r0 : (int)cap;
        const float* xc = x + (size_t)r0 * 256;
        dim3 g1(rows / 64, 2);
        k_enc1<<<g1, 256, 0, stream>>>(xc, pre_bias, WehHi, WehLo, b_eh, hHi, hLo, fcount);
        k_enc2_topk<<<rows / 64, 256, 0, stream>>>(hHi, hLo, WeoHi, WeoLo, b_eo, lat_b,
                                                   pre_out, mask_out, sl_out, t5v, t5i,
                                                   fcount, flist, r0);
        k_repair<<<256, 256, 0, stream>>>(xc, pre_bias, W_eh, b_eh, W_eo, b_eo, lat_b,
                                          fcount, flist, pre_out, mask_out, sl_out,
                                          t5v, t5i, r0);
        k_dec<<<rows / 64, 256, 0, stream>>>(t5v, t5i, WdhT, b_dh, WdoF, bias3, recon_out, r0);
    }
}

// Round 7
// 761.179 us; speedup vs baseline: 1.1293x; 1.1293x over previous
//
#include <hip/hip_runtime.h>
#include <stdint.h>

#define B_TOT 131072
#define GAP_TAU 2.5e-4f

typedef short v8s __attribute__((ext_vector_type(8)));
typedef float v4f __attribute__((ext_vector_type(4)));

__device__ __forceinline__ unsigned short f2bf(float f) {
    union { float f; unsigned u; } v; v.f = f;
    unsigned u = v.u;
    u += 0x7fffu + ((u >> 16) & 1u);      // RNE
    return (unsigned short)(u >> 16);
}
__device__ __forceinline__ float bf2f(unsigned short s) {
    union { unsigned u; float f; } v; v.u = ((unsigned)s) << 16;
    return v.f;
}
__device__ __forceinline__ unsigned pack2(float lo, float hi) {
    return (unsigned)f2bf(lo) | ((unsigned)f2bf(hi) << 16);
}

// ---------------- K0: prep (weights swizzle + fcount zero) ----------------
__global__ void k_prep(const float* __restrict__ W_dh,
                       const float* __restrict__ b_do,
                       const float* __restrict__ dec_b,
                       const float* __restrict__ pre_bias,
                       const float* __restrict__ W_do,
                       const float* __restrict__ W_eh,
                       const float* __restrict__ W_eo,
                       float* __restrict__ WdhT,
                       float* __restrict__ bias3,
                       unsigned short* __restrict__ Wdo_frag,
                       unsigned short* __restrict__ WehHi,
                       unsigned short* __restrict__ WehLo,
                       unsigned short* __restrict__ WeoHi,
                       unsigned short* __restrict__ WeoLo,
                       float* __restrict__ spars_out,
                       int* __restrict__ fcount)
{
    int t = blockIdx.x * blockDim.x + threadIdx.x;
    int nthr = gridDim.x * blockDim.x;
    for (int i = t; i < 512 * 64; i += nthr) {
        int h = i >> 6, l = i & 63;
        WdhT[l * 512 + h] = W_dh[i];
    }
    for (int g = t; g < 16384; g += nthr) {     // Wdo B-frag
        int lane = g & 63;
        int q = g >> 6;
        int nt = q >> 4, kc = q & 15;
        int col = nt * 16 + (lane & 15);
        int kbase = kc * 32 + (lane >> 4) * 8;
        const float* src = &W_do[(size_t)col * 512 + kbase];
        unsigned short* dst = &Wdo_frag[(size_t)g * 8];
        #pragma unroll
        for (int i = 0; i < 8; i++) dst[i] = f2bf(src[i]);
    }
    for (int g = t; g < 32 * 8 * 64; g += nthr) {   // W_eh hi/lo A-frag
        int lane = g & 63;
        int rem = g >> 6;
        int kcg = rem & 7, ct = rem >> 3;
        int c = ct * 16 + (lane & 15);
        int k = kcg * 32 + (lane >> 4) * 8;
        const float* src = &W_eh[(size_t)c * 256 + k];
        #pragma unroll
        for (int i = 0; i < 8; i++) {
            unsigned short hi = f2bf(src[i]);
            WehHi[(size_t)g * 8 + i] = hi;
            WehLo[(size_t)g * 8 + i] = f2bf(src[i] - bf2f(hi));
        }
    }
    for (int g = t; g < 4 * 16 * 64; g += nthr) {   // W_eo hi/lo A-frag
        int lane = g & 63;
        int rem = g >> 6;
        int kcg = rem & 15, lt = rem >> 4;
        int l = lt * 16 + (lane & 15);
        int k = kcg * 32 + (lane >> 4) * 8;
        const float* src = &W_eo[(size_t)l * 512 + k];
        #pragma unroll
        for (int i = 0; i < 8; i++) {
            unsigned short hi = f2bf(src[i]);
            WeoHi[(size_t)g * 8 + i] = hi;
            WeoLo[(size_t)g * 8 + i] = f2bf(src[i] - bf2f(hi));
        }
    }
    if (t < 256) bias3[t] = b_do[t] + dec_b[t] + pre_bias[t];
    if (t == 0) { spars_out[0] = 5.0f / 64.0f; *fcount = 0; }
}

// ---------------- K1: FUSED encoder: x -> h (LDS) -> pre_act -> top-5 -> outputs ----------------
// 32 rows/block, 512 thr = 8 waves. Wave w: phase B computes h cols [w*64,w*64+64);
// phase D computes pre_act partial over k-slice [w*64,w*64+64) from its OWN LDS h.
// Deterministic sequential cross-wave reduce. 64 KB static LDS, regions reused behind barriers.
__global__ __launch_bounds__(512, 2)
void k_enc(const float* __restrict__ x,
           const float* __restrict__ pre_bias,
           const unsigned short* __restrict__ WehHi,
           const unsigned short* __restrict__ WehLo,
           const float* __restrict__ b_eh,
           const unsigned short* __restrict__ WeoHi,
           const unsigned short* __restrict__ WeoLo,
           const float* __restrict__ b_eo,
           const float* __restrict__ lat_b,
           float* __restrict__ pre_out,
           float* __restrict__ mask_out,
           float* __restrict__ sl_out,
           float* __restrict__ t5v,          // global [B][5]
           int*   __restrict__ t5i,
           int*   __restrict__ fcount,
           int*   __restrict__ flist)
{
    __shared__ __align__(16) char smem[65536];
    const int t    = threadIdx.x;
    const int lane = t & 63;
    const int w    = t >> 6;        // 0..7
    const int rb   = blockIdx.x * 32;

    // ---- Phase A: stage x (32 r x 256 k) hi/lo bf16, swizzled. xH [0,16K), xL [16K,32K) ----
    {
        const int r  = t >> 4;          // 0..31
        const int kq = (t & 15) * 16;   // col start
        const float* xr = &x[(size_t)(rb + r) * 256 + kq];
        const float* pb = &pre_bias[kq];
        char* bh = smem + r * 512;
        char* bl = smem + 16384 + r * 512;
        const int sw = (r & 7) << 4;
        #pragma unroll
        for (int p = 0; p < 2; p++) {
            const float4 v0 = *reinterpret_cast<const float4*>(&xr[p * 8]);
            const float4 v1 = *reinterpret_cast<const float4*>(&xr[p * 8 + 4]);
            const float4 p0 = *reinterpret_cast<const float4*>(&pb[p * 8]);
            const float4 p1 = *reinterpret_cast<const float4*>(&pb[p * 8 + 4]);
            float f[8] = {v0.x - p0.x, v0.y - p0.y, v0.z - p0.z, v0.w - p0.w,
                          v1.x - p1.x, v1.y - p1.y, v1.z - p1.z, v1.w - p1.w};
            unsigned hi2[4], lo2[4];
            #pragma unroll
            for (int q = 0; q < 4; q++) {
                unsigned short h0 = f2bf(f[q * 2]), h1 = f2bf(f[q * 2 + 1]);
                hi2[q] = (unsigned)h0 | ((unsigned)h1 << 16);
                lo2[q] = (unsigned)f2bf(f[q * 2] - bf2f(h0)) | ((unsigned)f2bf(f[q * 2 + 1] - bf2f(h1)) << 16);
            }
            const int kb = (kq + p * 8) * 2;
            *reinterpret_cast<uint4*>(bh + (kb ^ sw)) = *reinterpret_cast<uint4*>(hi2);
            *reinterpret_cast<uint4*>(bl + (kb ^ sw)) = *reinterpret_cast<uint4*>(lo2);
        }
    }
    __syncthreads();

    // ---- Phase B: h = relu((x-pb) @ W_eh^T + b_eh), 3-product split-bf16 MFMA ----
    v4f acc[2][4];
    #pragma unroll
    for (int i = 0; i < 2; i++)
        #pragma unroll
        for (int j = 0; j < 4; j++) acc[i][j] = (v4f){0.f, 0.f, 0.f, 0.f};

    #pragma unroll 2
    for (int kc = 0; kc < 8; ++kc) {
        v8s wh[4], wl[4];
        #pragma unroll
        for (int ntl = 0; ntl < 4; ntl++) {
            const int ct = w * 4 + ntl;
            const size_t idx = ((size_t)(ct * 8 + kc) * 64 + lane) * 8;
            wh[ntl] = *reinterpret_cast<const v8s*>(&WehHi[idx]);
            wl[ntl] = *reinterpret_cast<const v8s*>(&WehLo[idx]);
        }
        v8s ah[2], al[2];
        #pragma unroll
        for (int mt = 0; mt < 2; mt++) {
            const int row = mt * 16 + (lane & 15);
            const int boff = row * 512 + ((kc * 64 + (lane >> 4) * 16) ^ ((row & 7) << 4));
            ah[mt] = *reinterpret_cast<const v8s*>(smem + boff);
            al[mt] = *reinterpret_cast<const v8s*>(smem + 16384 + boff);
        }
        #pragma unroll
        for (int mt = 0; mt < 2; mt++) {
            #pragma unroll
            for (int ntl = 0; ntl < 4; ntl++) {
                acc[mt][ntl] = __builtin_amdgcn_mfma_f32_16x16x32_bf16(wh[ntl], ah[mt], acc[mt][ntl], 0, 0, 0);
                acc[mt][ntl] = __builtin_amdgcn_mfma_f32_16x16x32_bf16(wl[ntl], ah[mt], acc[mt][ntl], 0, 0, 0);
                acc[mt][ntl] = __builtin_amdgcn_mfma_f32_16x16x32_bf16(wh[ntl], al[mt], acc[mt][ntl], 0, 0, 0);
            }
        }
    }
    __syncthreads();    // all x reads complete before h overwrites [0,64K)

    // ---- Phase C: relu+bias -> hi/lo bf16 into wave region [w*8K, w*8K+8K) ----
    {
        char* hb = smem + w * 8192;
        #pragma unroll
        for (int mt = 0; mt < 2; mt++) {
            const int row = mt * 16 + (lane & 15);
            const int sw = (row & 7) << 4;
            #pragma unroll
            for (int ntl = 0; ntl < 4; ntl++) {
                const int colw = ntl * 16 + (lane >> 4) * 4;    // col within wave slice
                const int c = w * 64 + colw;                     // global hidden col
                const float4 be = *reinterpret_cast<const float4*>(&b_eh[c]);
                float h0 = fmaxf(acc[mt][ntl][0] + be.x, 0.f);
                float h1 = fmaxf(acc[mt][ntl][1] + be.y, 0.f);
                float h2 = fmaxf(acc[mt][ntl][2] + be.z, 0.f);
                float h3 = fmaxf(acc[mt][ntl][3] + be.w, 0.f);
                unsigned short s0 = f2bf(h0), s1 = f2bf(h1), s2 = f2bf(h2), s3 = f2bf(h3);
                uint2 phi = { (unsigned)s0 | ((unsigned)s1 << 16), (unsigned)s2 | ((unsigned)s3 << 16) };
                uint2 plo = { (unsigned)f2bf(h0 - bf2f(s0)) | ((unsigned)f2bf(h1 - bf2f(s1)) << 16),
                              (unsigned)f2bf(h2 - bf2f(s2)) | ((unsigned)f2bf(h3 - bf2f(s3)) << 16) };
                const int off = row * 128 + ((colw * 2) ^ sw);
                *reinterpret_cast<uint2*>(hb + off)        = phi;
                *reinterpret_cast<uint2*>(hb + 4096 + off) = plo;
            }
        }
    }
    __syncthreads();

    // ---- Phase D: pre_act partial over k-slice [w*64,w*64+64), from own LDS h ----
    v4f acc2[4][2];
    #pragma unroll
    for (int i = 0; i < 4; i++)
        #pragma unroll
        for (int j = 0; j < 2; j++) acc2[i][j] = (v4f){0.f, 0.f, 0.f, 0.f};
    {
        const char* hb = smem + w * 8192;
        #pragma unroll
        for (int kc = 0; kc < 2; ++kc) {
            const int kcg = w * 2 + kc;
            v8s wh2[4], wl2[4];
            #pragma unroll
            for (int lt = 0; lt < 4; lt++) {
                const size_t idx = ((size_t)(lt * 16 + kcg) * 64 + lane) * 8;
                wh2[lt] = *reinterpret_cast<const v8s*>(&WeoHi[idx]);
                wl2[lt] = *reinterpret_cast<const v8s*>(&WeoLo[idx]);
            }
            v8s hh[2], hl[2];
            #pragma unroll
            for (int rt = 0; rt < 2; rt++) {
                const int row = rt * 16 + (lane & 15);
                const int off = row * 128 + ((kc * 64 + (lane >> 4) * 16) ^ ((row & 7) << 4));
                hh[rt] = *reinterpret_cast<const v8s*>(hb + off);
                hl[rt] = *reinterpret_cast<const v8s*>(hb + 4096 + off);
            }
            #pragma unroll
            for (int lt = 0; lt < 4; lt++) {
                #pragma unroll
                for (int rt = 0; rt < 2; rt++) {
                    acc2[lt][rt] = __builtin_amdgcn_mfma_f32_16x16x32_bf16(wh2[lt], hh[rt], acc2[lt][rt], 0, 0, 0);
                    acc2[lt][rt] = __builtin_amdgcn_mfma_f32_16x16x32_bf16(wl2[lt], hh[rt], acc2[lt][rt], 0, 0, 0);
                    acc2[lt][rt] = __builtin_amdgcn_mfma_f32_16x16x32_bf16(wh2[lt], hl[rt], acc2[lt][rt], 0, 0, 0);
                }
            }
        }
    }
    __syncthreads();    // all h reads complete before pa overwrites [0,8704)

    // ---- Sequential deterministic reduce into pa[32][68] at smem[0..8704) ----
    float* pa = (float*)smem;
    #pragma unroll 1
    for (int ww = 0; ww < 8; ++ww) {
        if (w == ww) {
            #pragma unroll
            for (int lt = 0; lt < 4; lt++)
                #pragma unroll
                for (int rt = 0; rt < 2; rt++) {
                    const int row  = rt * 16 + (lane & 15);
                    const int lat0 = lt * 16 + (lane >> 4) * 4;
                    #pragma unroll
                    for (int j = 0; j < 4; j++) {
                        float v = acc2[lt][rt][j];
                        if (ww == 0) v += b_eo[lat0 + j] + lat_b[lat0 + j];
                        else         v += pa[row * 68 + lat0 + j];
                        pa[row * 68 + lat0 + j] = v;
                    }
                }
        }
        __syncthreads();
    }

    unsigned long long* mbits = (unsigned long long*)(smem + 8704);
    // ---- top-5 + 6th gap check (t<32) ----
    if (t < 32) {
        const int r = t;
        unsigned long long used = 0ULL;
        float bv[5]; int bi[5];
        #pragma unroll
        for (int p = 0; p < 5; p++) {
            float best = -3.402823466e38f; int bidx = 0;
            for (int j = 0; j < 64; j++) {
                float v = pa[r * 68 + j];
                if (!((used >> j) & 1ULL) && v > best) { best = v; bidx = j; }
            }
            used |= 1ULL << bidx;
            bv[p] = best; bi[p] = bidx;
        }
        mbits[r] = used;
        const size_t gr = (size_t)(rb + r);
        #pragma unroll
        for (int p = 0; p < 5; p++) { t5v[gr * 5 + p] = bv[p]; t5i[gr * 5 + p] = bi[p]; }
        float v6 = -3.402823466e38f;
        for (int j = 0; j < 64; j++) {
            float v = pa[r * 68 + j];
            if (!((used >> j) & 1ULL) && v > v6) v6 = v;
        }
        if (bv[4] - v6 < GAP_TAU) {
            int slot = atomicAdd(fcount, 1);
            flist[slot] = rb + r;
        }
    }
    __syncthreads();
    // ---- coalesced output writes: 512 thr, 32 rows x 64 cols, 4 cols each ----
    {
        const int row = t >> 4, c0 = (t & 15) * 4;
        const size_t gr = (size_t)(rb + row);
        const unsigned long long bits = mbits[row];
        float p0 = pa[row * 68 + c0 + 0], p1 = pa[row * 68 + c0 + 1];
        float p2 = pa[row * 68 + c0 + 2], p3 = pa[row * 68 + c0 + 3];
        float m0 = (float)((bits >> (c0 + 0)) & 1ULL);
        float m1 = (float)((bits >> (c0 + 1)) & 1ULL);
        float m2 = (float)((bits >> (c0 + 2)) & 1ULL);
        float m3 = (float)((bits >> (c0 + 3)) & 1ULL);
        float4 pv = {p0, p1, p2, p3};
        float4 mv = {m0, m1, m2, m3};
        float4 sv = {m0 * p0, m1 * p1, m2 * p2, m3 * p3};
        *reinterpret_cast<float4*>(&pre_out[gr * 64 + c0])  = pv;
        *reinterpret_cast<float4*>(&mask_out[gr * 64 + c0]) = mv;
        *reinterpret_cast<float4*>(&sl_out[gr * 64 + c0])   = sv;
    }
}

// ---------------- K2b: fp32 exact repair of gap-flagged rows (global rows) ----------------
__global__ __launch_bounds__(256)
void k_repair(const float* __restrict__ x,
              const float* __restrict__ pre_bias,
              const float* __restrict__ W_eh,     // [512][256]
              const float* __restrict__ b_eh,
              const float* __restrict__ W_eo,     // [64][512]
              const float* __restrict__ b_eo,
              const float* __restrict__ lat_b,
              const int* __restrict__ fcount,
              const int* __restrict__ flist,
              float* __restrict__ pre_out,
              float* __restrict__ mask_out,
              float* __restrict__ sl_out,
              float* __restrict__ t5v,
              int*   __restrict__ t5i)
{
    __shared__ float xs[256];
    __shared__ float hs[512];
    __shared__ float part[64][4];
    __shared__ float pav[64];
    __shared__ unsigned long long bitsS;
    const int t = threadIdx.x;
    const int n = *fcount;
    #pragma unroll 1
    for (int it = blockIdx.x; it < n; it += gridDim.x) {
        const int r = flist[it];
        xs[t] = x[(size_t)r * 256 + t] - pre_bias[t];
        __syncthreads();
        #pragma unroll 1
        for (int j = t; j < 512; j += 256) {
            const float* wr = &W_eh[(size_t)j * 256];
            float acc = 0.f;
            #pragma unroll
            for (int k = 0; k < 256; k += 4) {
                const float4 wv = *reinterpret_cast<const float4*>(&wr[k]);
                acc = fmaf(wv.x, xs[k + 0], acc);
                acc = fmaf(wv.y, xs[k + 1], acc);
                acc = fmaf(wv.z, xs[k + 2], acc);
                acc = fmaf(wv.w, xs[k + 3], acc);
            }
            hs[j] = fmaxf(acc + b_eh[j], 0.f);
        }
        __syncthreads();
        {
            const int l = t & 63, q = t >> 6;
            const float* wr = &W_eo[(size_t)l * 512 + q * 128];
            const float* hp = &hs[q * 128];
            float acc = 0.f;
            #pragma unroll
            for (int k = 0; k < 128; k += 4) {
                const float4 wv = *reinterpret_cast<const float4*>(&wr[k]);
                acc = fmaf(wv.x, hp[k + 0], acc);
                acc = fmaf(wv.y, hp[k + 1], acc);
                acc = fmaf(wv.z, hp[k + 2], acc);
                acc = fmaf(wv.w, hp[k + 3], acc);
            }
            part[l][q] = acc;
        }
        __syncthreads();
        if (t < 64)
            pav[t] = ((part[t][0] + part[t][1]) + (part[t][2] + part[t][3])) + b_eo[t] + lat_b[t];
        __syncthreads();
        if (t == 0) {
            unsigned long long used = 0ULL;
            const size_t gr = (size_t)r;
            #pragma unroll
            for (int p = 0; p < 5; p++) {
                float best = -3.402823466e38f; int bidx = 0;
                for (int j = 0; j < 64; j++) {
                    float v = pav[j];
                    if (!((used >> j) & 1ULL) && v > best) { best = v; bidx = j; }
                }
                used |= 1ULL << bidx;
                t5v[gr * 5 + p] = best; t5i[gr * 5 + p] = bidx;
            }
            bitsS = used;
        }
        __syncthreads();
        if (t < 64) {
            const size_t gr = (size_t)r;
            const float v = pav[t];
            const float m = (float)((bitsS >> t) & 1ULL);
            pre_out[gr * 64 + t]  = v;
            mask_out[gr * 64 + t] = m;
            sl_out[gr * 64 + t]   = m * v;
        }
        __syncthreads();
    }
}

// ---------------- K3: recon via bf16 MFMA (validated; global t5) ----------------
__global__ __launch_bounds__(256)
void k_dec(const float* __restrict__ t5v, const int* __restrict__ t5i,
           const float* __restrict__ WdhT,        // [64][512] fp32
           const float* __restrict__ b_dh,
           const unsigned short* __restrict__ Wdo_frag,
           const float* __restrict__ bias3,
           float* __restrict__ recon)             // global [B][256]
{
    __shared__ __align__(16) short sA[64 * 136];
    __shared__ float svv[64][5];
    __shared__ int   sii[64][5];
    const int t    = threadIdx.x;
    const int rb   = blockIdx.x * 64;
    const int lane = t & 63;
    const int w    = t >> 6;
    const int r    = t & 63;

    for (int i = t; i < 320; i += 256) {
        int rr = i / 5, p = i % 5;
        size_t lr = (size_t)(rb + rr);
        svv[rr][p] = t5v[lr * 5 + p];
        sii[rr][p] = t5i[lr * 5 + p];
    }
    __syncthreads();

    v4f acc[4][4];
    #pragma unroll
    for (int i = 0; i < 4; i++)
        #pragma unroll
        for (int j = 0; j < 4; j++) acc[i][j] = (v4f){0.f, 0.f, 0.f, 0.f};

    #pragma unroll 1
    for (int c = 0; c < 4; ++c) {
        const int k0 = c * 128;
        {
            const int kbase = k0 + w * 32;
            float a[32];
            #pragma unroll
            for (int q = 0; q < 8; q++) {
                const float4 bd = *reinterpret_cast<const float4*>(&b_dh[kbase + q * 4]);
                a[q * 4 + 0] = bd.x; a[q * 4 + 1] = bd.y; a[q * 4 + 2] = bd.z; a[q * 4 + 3] = bd.w;
            }
            #pragma unroll
            for (int p = 0; p < 5; p++) {
                const float s = svv[r][p];
                const float4* wp = reinterpret_cast<const float4*>(&WdhT[(size_t)sii[r][p] * 512 + kbase]);
                #pragma unroll
                for (int q = 0; q < 8; q++) {
                    const float4 wv = wp[q];
                    a[q * 4 + 0] = fmaf(s, wv.x, a[q * 4 + 0]);
                    a[q * 4 + 1] = fmaf(s, wv.y, a[q * 4 + 1]);
                    a[q * 4 + 2] = fmaf(s, wv.z, a[q * 4 + 2]);
                    a[q * 4 + 3] = fmaf(s, wv.w, a[q * 4 + 3]);
                }
            }
            char* base = (char*)sA + r * 272 + w * 64;
            #pragma unroll
            for (int q2 = 0; q2 < 4; q2++) {
                uint4 o;
                o.x = pack2(fmaxf(a[q2 * 8 + 0], 0.f), fmaxf(a[q2 * 8 + 1], 0.f));
                o.y = pack2(fmaxf(a[q2 * 8 + 2], 0.f), fmaxf(a[q2 * 8 + 3], 0.f));
                o.z = pack2(fmaxf(a[q2 * 8 + 4], 0.f), fmaxf(a[q2 * 8 + 5], 0.f));
                o.w = pack2(fmaxf(a[q2 * 8 + 6], 0.f), fmaxf(a[q2 * 8 + 7], 0.f));
                *reinterpret_cast<uint4*>(base + q2 * 16) = o;
            }
        }
        __syncthreads();
        #pragma unroll
        for (int kcl = 0; kcl < 4; ++kcl) {
            const int kcg = c * 4 + kcl;
            v8s af[4];
            #pragma unroll
            for (int mt = 0; mt < 4; mt++)
                af[mt] = *reinterpret_cast<const v8s*>(
                    (char*)sA + (mt * 16 + (lane & 15)) * 272 + kcl * 64 + (lane >> 4) * 16);
            v8s bf[4];
            #pragma unroll
            for (int ntl = 0; ntl < 4; ntl++) {
                const int ntg = w * 4 + ntl;
                bf[ntl] = *reinterpret_cast<const v8s*>(
                    Wdo_frag + ((size_t)(ntg * 16 + kcg) * 64 + lane) * 8);
            }
            #pragma unroll
            for (int mt = 0; mt < 4; mt++)
                #pragma unroll
                for (int ntl = 0; ntl < 4; ntl++)
                    acc[mt][ntl] = __builtin_amdgcn_mfma_f32_16x16x32_bf16(
                        af[mt], bf[ntl], acc[mt][ntl], 0, 0, 0);
        }
        __syncthreads();
    }
    #pragma unroll
    for (int ntl = 0; ntl < 4; ntl++) {
        const int col = w * 64 + ntl * 16 + (lane & 15);
        const float bz = bias3[col];
        #pragma unroll
        for (int mt = 0; mt < 4; mt++) {
            #pragma unroll
            for (int j = 0; j < 4; j++) {
                const size_t row = (size_t)(rb + mt * 16 + (lane >> 4) * 4 + j);
                recon[row * 256 + col] = acc[mt][ntl][j] + bz;
            }
        }
    }
}

// ---------------- host ----------------
extern "C" void kernel_launch(void* const* d_in, const int* in_sizes, int n_in,
                              void* d_out, int out_size, void* d_ws, size_t ws_size,
                              hipStream_t stream)
{
    const float* x        = (const float*)d_in[0];
    const float* pre_bias = (const float*)d_in[1];
    const float* W_eh     = (const float*)d_in[2];
    const float* b_eh     = (const float*)d_in[3];
    const float* W_eo     = (const float*)d_in[4];
    const float* b_eo     = (const float*)d_in[5];
    const float* lat_b    = (const float*)d_in[6];
    const float* W_dh     = (const float*)d_in[7];
    const float* b_dh     = (const float*)d_in[8];
    const float* W_do     = (const float*)d_in[9];
    const float* b_do     = (const float*)d_in[10];
    const float* dec_b    = (const float*)d_in[11];

    float* out = (float*)d_out;
    float* recon_out = out;
    float* sl_out    = out + (size_t)B_TOT * 256;
    float* pre_out   = sl_out + (size_t)B_TOT * 64;
    float* mask_out  = pre_out + (size_t)B_TOT * 64;
    float* spars_out = mask_out + (size_t)B_TOT * 64;

    // ws: WdhT 128K | bias3 1K | WdoF 256K | WehHi 256K | WehLo 256K | WeoHi 64K | WeoLo 64K
    //     | fcount 64B | flist 512K | t5v 2.5M | t5i 2.5M   (~6.8 MB total)
    char* ws = (char*)d_ws;
    float* WdhT           = (float*)ws;
    float* bias3          = (float*)(ws + 131072);
    unsigned short* WdoF  = (unsigned short*)(ws + 132096);
    unsigned short* WehHi = (unsigned short*)(ws + 394240);
    unsigned short* WehLo = (unsigned short*)(ws + 656384);
    unsigned short* WeoHi = (unsigned short*)(ws + 918528);
    unsigned short* WeoLo = (unsigned short*)(ws + 984064);
    int* fcount           = (int*)(ws + 1049600);
    int* flist            = (int*)(ws + 1049664);
    float* t5v            = (float*)(ws + 1049664 + 524288);
    int*   t5i            = (int*)  (ws + 1049664 + 524288 + (size_t)B_TOT * 20);

    k_prep<<<32, 256, 0, stream>>>(W_dh, b_do, dec_b, pre_bias, W_do, W_eh, W_eo,
                                   WdhT, bias3, WdoF, WehHi, WehLo, WeoHi, WeoLo,
                                   spars_out, fcount);

    k_enc<<<B_TOT / 32, 512, 0, stream>>>(x, pre_bias, WehHi, WehLo, b_eh,
                                          WeoHi, WeoLo, b_eo, lat_b,
                                          pre_out, mask_out, sl_out, t5v, t5i,
                                          fcount, flist);

    k_repair<<<256, 256, 0, stream>>>(x, pre_bias, W_eh, b_eh, W_eo, b_eo, lat_b,
                                      fcount, flist, pre_out, mask_out, sl_out,
                                      t5v, t5i);

    k_dec<<<B_TOT / 64, 256, 0, stream>>>(t5v, t5i, WdhT, b_dh, WdoF, bias3, recon_out);
}

// Round 8
// 677.777 us; speedup vs baseline: 1.2683x; 1.1231x over previous
//
#include <hip/hip_runtime.h>
#include <stdint.h>

#define B_TOT 131072
#define GAP_TAU 2.5e-4f

typedef short v8s __attribute__((ext_vector_type(8)));
typedef float v4f __attribute__((ext_vector_type(4)));

__device__ __forceinline__ unsigned short f2bf(float f) {
    union { float f; unsigned u; } v; v.f = f;
    unsigned u = v.u;
    u += 0x7fffu + ((u >> 16) & 1u);      // RNE
    return (unsigned short)(u >> 16);
}
__device__ __forceinline__ float bf2f(unsigned short s) {
    union { unsigned u; float f; } v; v.u = ((unsigned)s) << 16;
    return v.f;
}
__device__ __forceinline__ unsigned pack2(float lo, float hi) {
    return (unsigned)f2bf(lo) | ((unsigned)f2bf(hi) << 16);
}

// ---------------- K0: prep (weights swizzle + fcount zero) ----------------
__global__ void k_prep(const float* __restrict__ W_dh,
                       const float* __restrict__ b_do,
                       const float* __restrict__ dec_b,
                       const float* __restrict__ pre_bias,
                       const float* __restrict__ W_do,
                       const float* __restrict__ W_eh,
                       const float* __restrict__ W_eo,
                       float* __restrict__ WdhT,
                       float* __restrict__ bias3,
                       unsigned short* __restrict__ Wdo_frag,
                       unsigned short* __restrict__ WehHi,
                       unsigned short* __restrict__ WehLo,
                       unsigned short* __restrict__ WeoHi,
                       unsigned short* __restrict__ WeoLo,
                       float* __restrict__ spars_out,
                       int* __restrict__ fcount)
{
    int t = blockIdx.x * blockDim.x + threadIdx.x;
    int nthr = gridDim.x * blockDim.x;
    for (int i = t; i < 512 * 64; i += nthr) {
        int h = i >> 6, l = i & 63;
        WdhT[l * 512 + h] = W_dh[i];
    }
    for (int g = t; g < 16384; g += nthr) {     // Wdo B-frag
        int lane = g & 63;
        int q = g >> 6;
        int nt = q >> 4, kc = q & 15;
        int col = nt * 16 + (lane & 15);
        int kbase = kc * 32 + (lane >> 4) * 8;
        const float* src = &W_do[(size_t)col * 512 + kbase];
        unsigned short* dst = &Wdo_frag[(size_t)g * 8];
        #pragma unroll
        for (int i = 0; i < 8; i++) dst[i] = f2bf(src[i]);
    }
    for (int g = t; g < 32 * 8 * 64; g += nthr) {   // W_eh hi/lo A-frag
        int lane = g & 63;
        int rem = g >> 6;
        int kcg = rem & 7, ct = rem >> 3;
        int c = ct * 16 + (lane & 15);
        int k = kcg * 32 + (lane >> 4) * 8;
        const float* src = &W_eh[(size_t)c * 256 + k];
        #pragma unroll
        for (int i = 0; i < 8; i++) {
            unsigned short hi = f2bf(src[i]);
            WehHi[(size_t)g * 8 + i] = hi;
            WehLo[(size_t)g * 8 + i] = f2bf(src[i] - bf2f(hi));
        }
    }
    for (int g = t; g < 4 * 16 * 64; g += nthr) {   // W_eo hi/lo A-frag
        int lane = g & 63;
        int rem = g >> 6;
        int kcg = rem & 15, lt = rem >> 4;
        int l = lt * 16 + (lane & 15);
        int k = kcg * 32 + (lane >> 4) * 8;
        const float* src = &W_eo[(size_t)l * 512 + k];
        #pragma unroll
        for (int i = 0; i < 8; i++) {
            unsigned short hi = f2bf(src[i]);
            WeoHi[(size_t)g * 8 + i] = hi;
            WeoLo[(size_t)g * 8 + i] = f2bf(src[i] - bf2f(hi));
        }
    }
    if (t < 256) bias3[t] = b_do[t] + dec_b[t] + pre_bias[t];
    if (t == 0) { spars_out[0] = 5.0f / 64.0f; *fcount = 0; }
}

// ---------------- K1: h = relu((x-pb) @ W_eh^T + b_eh), split-bf16 MFMA ----------------
// 64 rows x ALL 512 cols per block; 512 thr = 8 waves, wave w -> cols w*64..+64.
// x staged ONCE in frag layout (aH/aL [kc][mt][lane][8], 64 KB) -> ONE barrier ->
// barrier-free unrolled MFMA loop (W frags streamed from L2).
__global__ __launch_bounds__(512, 2)
void k_enc1(const float* __restrict__ x,
            const float* __restrict__ pre_bias,
            const unsigned short* __restrict__ WehHi,
            const unsigned short* __restrict__ WehLo,
            const float* __restrict__ b_eh,
            unsigned short* __restrict__ hHi,   // [B][512]
            unsigned short* __restrict__ hLo)
{
    __shared__ __align__(16) unsigned short aH[8 * 4 * 64 * 8];  // 32 KB
    __shared__ __align__(16) unsigned short aL[8 * 4 * 64 * 8];  // 32 KB
    const int t    = threadIdx.x;
    const int lane = t & 63;
    const int w    = t >> 6;        // 0..7
    const int rb   = blockIdx.x * 64;

    // ---- stage x (64 r x 256 k) hi/lo into frag layout ----
    #pragma unroll
    for (int i = 0; i < 4; i++) {
        const int f    = t + i * 512;       // 0..2047
        const int srow = f >> 5;            // 0..63
        const int kc   = (f >> 2) & 7;      // 0..7
        const int skq  = f & 3;             // 0..3
        const float* xp = &x[(size_t)(rb + srow) * 256 + kc * 32 + skq * 8];
        const float* pp = &pre_bias[kc * 32 + skq * 8];
        const float4 v0 = *reinterpret_cast<const float4*>(xp);
        const float4 v1 = *reinterpret_cast<const float4*>(xp + 4);
        const float4 p0 = *reinterpret_cast<const float4*>(pp);
        const float4 p1 = *reinterpret_cast<const float4*>(pp + 4);
        float fv[8] = {v0.x - p0.x, v0.y - p0.y, v0.z - p0.z, v0.w - p0.w,
                       v1.x - p1.x, v1.y - p1.y, v1.z - p1.z, v1.w - p1.w};
        unsigned hi2[4], lo2[4];
        #pragma unroll
        for (int q = 0; q < 4; q++) {
            unsigned short h0 = f2bf(fv[q * 2]), h1 = f2bf(fv[q * 2 + 1]);
            hi2[q] = (unsigned)h0 | ((unsigned)h1 << 16);
            lo2[q] = (unsigned)f2bf(fv[q * 2] - bf2f(h0)) | ((unsigned)f2bf(fv[q * 2 + 1] - bf2f(h1)) << 16);
        }
        const int mt = srow >> 4;
        const int ln = skq * 16 + (srow & 15);
        *reinterpret_cast<uint4*>(&aH[((kc * 4 + mt) * 64 + ln) * 8]) = *reinterpret_cast<uint4*>(hi2);
        *reinterpret_cast<uint4*>(&aL[((kc * 4 + mt) * 64 + ln) * 8]) = *reinterpret_cast<uint4*>(lo2);
    }
    __syncthreads();

    v4f acc[4][4];
    #pragma unroll
    for (int i = 0; i < 4; i++)
        #pragma unroll
        for (int j = 0; j < 4; j++) acc[i][j] = (v4f){0.f, 0.f, 0.f, 0.f};

    // ---- barrier-free MFMA loop ----
    #pragma unroll 2
    for (int kc = 0; kc < 8; ++kc) {
        v8s wh[4], wl[4];
        #pragma unroll
        for (int ntl = 0; ntl < 4; ntl++) {
            const int ct = w * 4 + ntl;
            const size_t idx = ((size_t)(ct * 8 + kc) * 64 + lane) * 8;
            wh[ntl] = *reinterpret_cast<const v8s*>(&WehHi[idx]);
            wl[ntl] = *reinterpret_cast<const v8s*>(&WehLo[idx]);
        }
        v8s ah[4], al[4];
        #pragma unroll
        for (int mt = 0; mt < 4; mt++) {
            const int off = ((kc * 4 + mt) * 64 + lane) * 8;
            ah[mt] = *reinterpret_cast<const v8s*>(&aH[off]);
            al[mt] = *reinterpret_cast<const v8s*>(&aL[off]);
        }
        #pragma unroll
        for (int mt = 0; mt < 4; mt++) {
            #pragma unroll
            for (int ntl = 0; ntl < 4; ntl++) {
                acc[mt][ntl] = __builtin_amdgcn_mfma_f32_16x16x32_bf16(wh[ntl], ah[mt], acc[mt][ntl], 0, 0, 0);
                acc[mt][ntl] = __builtin_amdgcn_mfma_f32_16x16x32_bf16(wl[ntl], ah[mt], acc[mt][ntl], 0, 0, 0);
                acc[mt][ntl] = __builtin_amdgcn_mfma_f32_16x16x32_bf16(wh[ntl], al[mt], acc[mt][ntl], 0, 0, 0);
            }
        }
    }
    // ---- epilogue: relu(acc + b_eh) -> hi/lo planes ----
    #pragma unroll
    for (int mt = 0; mt < 4; mt++) {
        const size_t r = (size_t)(rb + mt * 16 + (lane & 15));
        #pragma unroll
        for (int ntl = 0; ntl < 4; ntl++) {
            const int c = w * 64 + ntl * 16 + (lane >> 4) * 4;
            const float4 be = *reinterpret_cast<const float4*>(&b_eh[c]);
            float h0 = fmaxf(acc[mt][ntl][0] + be.x, 0.f);
            float h1 = fmaxf(acc[mt][ntl][1] + be.y, 0.f);
            float h2 = fmaxf(acc[mt][ntl][2] + be.z, 0.f);
            float h3 = fmaxf(acc[mt][ntl][3] + be.w, 0.f);
            unsigned short s0 = f2bf(h0), s1 = f2bf(h1), s2 = f2bf(h2), s3 = f2bf(h3);
            uint2 phi = { (unsigned)s0 | ((unsigned)s1 << 16), (unsigned)s2 | ((unsigned)s3 << 16) };
            uint2 plo = { (unsigned)f2bf(h0 - bf2f(s0)) | ((unsigned)f2bf(h1 - bf2f(s1)) << 16),
                          (unsigned)f2bf(h2 - bf2f(s2)) | ((unsigned)f2bf(h3 - bf2f(s3)) << 16) };
            *reinterpret_cast<uint2*>(&hHi[r * 512 + c]) = phi;
            *reinterpret_cast<uint2*>(&hLo[r * 512 + c]) = plo;
        }
    }
}

// ---------------- K2: pre_act (split-bf16 MFMA); top-5; gap-flag; outputs ----------------
__global__ __launch_bounds__(256, 4)
void k_enc2_topk(const unsigned short* __restrict__ hHi,
                 const unsigned short* __restrict__ hLo,
                 const unsigned short* __restrict__ WeoHi,
                 const unsigned short* __restrict__ WeoLo,
                 const float* __restrict__ b_eo,
                 const float* __restrict__ lat_b,
                 float* __restrict__ pre_out,
                 float* __restrict__ mask_out,
                 float* __restrict__ sl_out,
                 float* __restrict__ t5v,          // global [B][5]
                 int*   __restrict__ t5i,
                 int*   __restrict__ fcount,
                 int*   __restrict__ flist)
{
    __shared__ float pa[64][68];
    __shared__ unsigned long long mbits[64];
    const int t    = threadIdx.x;
    const int lane = t & 63;
    const int w    = t >> 6;
    const int rb   = blockIdx.x * 64;

    v4f acc[4];
    #pragma unroll
    for (int i = 0; i < 4; i++) acc[i] = (v4f){0.f, 0.f, 0.f, 0.f};

    #pragma unroll 1
    for (int kcl = 0; kcl < 16; ++kcl) {
        const size_t hoff = (size_t)(rb + w * 16 + (lane & 15)) * 512 + kcl * 32 + (lane >> 4) * 8;
        const v8s hh = *reinterpret_cast<const v8s*>(&hHi[hoff]);
        const v8s hl = *reinterpret_cast<const v8s*>(&hLo[hoff]);
        #pragma unroll
        for (int lt = 0; lt < 4; lt++) {
            const size_t idx = ((size_t)(lt * 16 + kcl) * 64 + lane) * 8;
            const v8s wh = *reinterpret_cast<const v8s*>(&WeoHi[idx]);
            const v8s wl = *reinterpret_cast<const v8s*>(&WeoLo[idx]);
            acc[lt] = __builtin_amdgcn_mfma_f32_16x16x32_bf16(wh, hh, acc[lt], 0, 0, 0);
            acc[lt] = __builtin_amdgcn_mfma_f32_16x16x32_bf16(wl, hh, acc[lt], 0, 0, 0);
            acc[lt] = __builtin_amdgcn_mfma_f32_16x16x32_bf16(wh, hl, acc[lt], 0, 0, 0);
        }
    }
    #pragma unroll
    for (int lt = 0; lt < 4; lt++) {
        const int l0 = lt * 16 + ((lane >> 4) << 2);
        const float4 be = *reinterpret_cast<const float4*>(&b_eo[l0]);
        const float4 lb = *reinterpret_cast<const float4*>(&lat_b[l0]);
        float4 o;
        o.x = acc[lt][0] + be.x + lb.x;
        o.y = acc[lt][1] + be.y + lb.y;
        o.z = acc[lt][2] + be.z + lb.z;
        o.w = acc[lt][3] + be.w + lb.w;
        *reinterpret_cast<float4*>(&pa[w * 16 + (lane & 15)][l0]) = o;
    }
    __syncthreads();
    if (t < 64) {
        int r = t;
        unsigned long long used = 0ULL;
        float bv[5]; int bi[5];
        #pragma unroll
        for (int p = 0; p < 5; p++) {
            float best = -3.402823466e38f; int bidx = 0;
            for (int j = 0; j < 64; j++) {
                float v = pa[r][j];
                if (!((used >> j) & 1ULL) && v > best) { best = v; bidx = j; }
            }
            used |= 1ULL << bidx;
            bv[p] = best; bi[p] = bidx;
        }
        mbits[r] = used;
        size_t gr = (size_t)(rb + r);
        #pragma unroll
        for (int p = 0; p < 5; p++) { t5v[gr * 5 + p] = bv[p]; t5i[gr * 5 + p] = bi[p]; }
        float v6 = -3.402823466e38f;
        for (int j = 0; j < 64; j++) {
            float v = pa[r][j];
            if (!((used >> j) & 1ULL) && v > v6) v6 = v;
        }
        if (bv[4] - v6 < GAP_TAU) {
            int slot = atomicAdd(fcount, 1);
            flist[slot] = rb + r;
        }
    }
    __syncthreads();
    {
        int row = t >> 2, c0 = (t & 3) * 16;
        size_t gr = (size_t)(rb + row);
        unsigned long long bits = mbits[row];
        #pragma unroll
        for (int g = 0; g < 4; g++) {
            int c = c0 + g * 4;
            float p0 = pa[row][c + 0], p1 = pa[row][c + 1], p2 = pa[row][c + 2], p3 = pa[row][c + 3];
            float m0 = (float)((bits >> (c + 0)) & 1ULL);
            float m1 = (float)((bits >> (c + 1)) & 1ULL);
            float m2 = (float)((bits >> (c + 2)) & 1ULL);
            float m3 = (float)((bits >> (c + 3)) & 1ULL);
            float4 pv = {p0, p1, p2, p3};
            float4 mv = {m0, m1, m2, m3};
            float4 sv = {m0 * p0, m1 * p1, m2 * p2, m3 * p3};
            *reinterpret_cast<float4*>(&pre_out[gr * 64 + c])  = pv;
            *reinterpret_cast<float4*>(&mask_out[gr * 64 + c]) = mv;
            *reinterpret_cast<float4*>(&sl_out[gr * 64 + c])   = sv;
        }
    }
}

// ---------------- K2b: fp32 exact repair of gap-flagged rows ----------------
__global__ __launch_bounds__(256)
void k_repair(const float* __restrict__ x,
              const float* __restrict__ pre_bias,
              const float* __restrict__ W_eh,     // [512][256]
              const float* __restrict__ b_eh,
              const float* __restrict__ W_eo,     // [64][512]
              const float* __restrict__ b_eo,
              const float* __restrict__ lat_b,
              const int* __restrict__ fcount,
              const int* __restrict__ flist,
              float* __restrict__ pre_out,
              float* __restrict__ mask_out,
              float* __restrict__ sl_out,
              float* __restrict__ t5v,
              int*   __restrict__ t5i)
{
    __shared__ float xs[256];
    __shared__ float hs[512];
    __shared__ float part[64][4];
    __shared__ float pav[64];
    __shared__ unsigned long long bitsS;
    const int t = threadIdx.x;
    const int n = *fcount;
    #pragma unroll 1
    for (int it = blockIdx.x; it < n; it += gridDim.x) {
        const int r = flist[it];
        xs[t] = x[(size_t)r * 256 + t] - pre_bias[t];
        __syncthreads();
        #pragma unroll 1
        for (int j = t; j < 512; j += 256) {
            const float* wr = &W_eh[(size_t)j * 256];
            float acc = 0.f;
            #pragma unroll
            for (int k = 0; k < 256; k += 4) {
                const float4 wv = *reinterpret_cast<const float4*>(&wr[k]);
                acc = fmaf(wv.x, xs[k + 0], acc);
                acc = fmaf(wv.y, xs[k + 1], acc);
                acc = fmaf(wv.z, xs[k + 2], acc);
                acc = fmaf(wv.w, xs[k + 3], acc);
            }
            hs[j] = fmaxf(acc + b_eh[j], 0.f);
        }
        __syncthreads();
        {
            const int l = t & 63, q = t >> 6;
            const float* wr = &W_eo[(size_t)l * 512 + q * 128];
            const float* hp = &hs[q * 128];
            float acc = 0.f;
            #pragma unroll
            for (int k = 0; k < 128; k += 4) {
                const float4 wv = *reinterpret_cast<const float4*>(&wr[k]);
                acc = fmaf(wv.x, hp[k + 0], acc);
                acc = fmaf(wv.y, hp[k + 1], acc);
                acc = fmaf(wv.z, hp[k + 2], acc);
                acc = fmaf(wv.w, hp[k + 3], acc);
            }
            part[l][q] = acc;
        }
        __syncthreads();
        if (t < 64)
            pav[t] = ((part[t][0] + part[t][1]) + (part[t][2] + part[t][3])) + b_eo[t] + lat_b[t];
        __syncthreads();
        if (t == 0) {
            unsigned long long used = 0ULL;
            const size_t gr = (size_t)r;
            #pragma unroll
            for (int p = 0; p < 5; p++) {
                float best = -3.402823466e38f; int bidx = 0;
                for (int j = 0; j < 64; j++) {
                    float v = pav[j];
                    if (!((used >> j) & 1ULL) && v > best) { best = v; bidx = j; }
                }
                used |= 1ULL << bidx;
                t5v[gr * 5 + p] = best; t5i[gr * 5 + p] = bidx;
            }
            bitsS = used;
        }
        __syncthreads();
        if (t < 64) {
            const size_t gr = (size_t)r;
            const float v = pav[t];
            const float m = (float)((bitsS >> t) & 1ULL);
            pre_out[gr * 64 + t]  = v;
            mask_out[gr * 64 + t] = m;
            sl_out[gr * 64 + t]   = m * v;
        }
        __syncthreads();
    }
}

// ---------------- K3: recon via bf16 MFMA (validated) ----------------
__global__ __launch_bounds__(256)
void k_dec(const float* __restrict__ t5v, const int* __restrict__ t5i,
           const float* __restrict__ WdhT,        // [64][512] fp32
           const float* __restrict__ b_dh,
           const unsigned short* __restrict__ Wdo_frag,
           const float* __restrict__ bias3,
           float* __restrict__ recon)             // global [B][256]
{
    __shared__ __align__(16) short sA[64 * 136];
    __shared__ float svv[64][5];
    __shared__ int   sii[64][5];
    const int t    = threadIdx.x;
    const int rb   = blockIdx.x * 64;
    const int lane = t & 63;
    const int w    = t >> 6;
    const int r    = t & 63;

    for (int i = t; i < 320; i += 256) {
        int rr = i / 5, p = i % 5;
        size_t lr = (size_t)(rb + rr);
        svv[rr][p] = t5v[lr * 5 + p];
        sii[rr][p] = t5i[lr * 5 + p];
    }
    __syncthreads();

    v4f acc[4][4];
    #pragma unroll
    for (int i = 0; i < 4; i++)
        #pragma unroll
        for (int j = 0; j < 4; j++) acc[i][j] = (v4f){0.f, 0.f, 0.f, 0.f};

    #pragma unroll 1
    for (int c = 0; c < 4; ++c) {
        const int k0 = c * 128;
        {
            const int kbase = k0 + w * 32;
            float a[32];
            #pragma unroll
            for (int q = 0; q < 8; q++) {
                const float4 bd = *reinterpret_cast<const float4*>(&b_dh[kbase + q * 4]);
                a[q * 4 + 0] = bd.x; a[q * 4 + 1] = bd.y; a[q * 4 + 2] = bd.z; a[q * 4 + 3] = bd.w;
            }
            #pragma unroll
            for (int p = 0; p < 5; p++) {
                const float s = svv[r][p];
                const float4* wp = reinterpret_cast<const float4*>(&WdhT[(size_t)sii[r][p] * 512 + kbase]);
                #pragma unroll
                for (int q = 0; q < 8; q++) {
                    const float4 wv = wp[q];
                    a[q * 4 + 0] = fmaf(s, wv.x, a[q * 4 + 0]);
                    a[q * 4 + 1] = fmaf(s, wv.y, a[q * 4 + 1]);
                    a[q * 4 + 2] = fmaf(s, wv.z, a[q * 4 + 2]);
                    a[q * 4 + 3] = fmaf(s, wv.w, a[q * 4 + 3]);
                }
            }
            char* base = (char*)sA + r * 272 + w * 64;
            #pragma unroll
            for (int q2 = 0; q2 < 4; q2++) {
                uint4 o;
                o.x = pack2(fmaxf(a[q2 * 8 + 0], 0.f), fmaxf(a[q2 * 8 + 1], 0.f));
                o.y = pack2(fmaxf(a[q2 * 8 + 2], 0.f), fmaxf(a[q2 * 8 + 3], 0.f));
                o.z = pack2(fmaxf(a[q2 * 8 + 4], 0.f), fmaxf(a[q2 * 8 + 5], 0.f));
                o.w = pack2(fmaxf(a[q2 * 8 + 6], 0.f), fmaxf(a[q2 * 8 + 7], 0.f));
                *reinterpret_cast<uint4*>(base + q2 * 16) = o;
            }
        }
        __syncthreads();
        #pragma unroll
        for (int kcl = 0; kcl < 4; ++kcl) {
            const int kcg = c * 4 + kcl;
            v8s af[4];
            #pragma unroll
            for (int mt = 0; mt < 4; mt++)
                af[mt] = *reinterpret_cast<const v8s*>(
                    (char*)sA + (mt * 16 + (lane & 15)) * 272 + kcl * 64 + (lane >> 4) * 16);
            v8s bf[4];
            #pragma unroll
            for (int ntl = 0; ntl < 4; ntl++) {
                const int ntg = w * 4 + ntl;
                bf[ntl] = *reinterpret_cast<const v8s*>(
                    Wdo_frag + ((size_t)(ntg * 16 + kcg) * 64 + lane) * 8);
            }
            #pragma unroll
            for (int mt = 0; mt < 4; mt++)
                #pragma unroll
                for (int ntl = 0; ntl < 4; ntl++)
                    acc[mt][ntl] = __builtin_amdgcn_mfma_f32_16x16x32_bf16(
                        af[mt], bf[ntl], acc[mt][ntl], 0, 0, 0);
        }
        __syncthreads();
    }
    #pragma unroll
    for (int ntl = 0; ntl < 4; ntl++) {
        const int col = w * 64 + ntl * 16 + (lane & 15);
        const float bz = bias3[col];
        #pragma unroll
        for (int mt = 0; mt < 4; mt++) {
            #pragma unroll
            for (int j = 0; j < 4; j++) {
                const size_t row = (size_t)(rb + mt * 16 + (lane >> 4) * 4 + j);
                recon[row * 256 + col] = acc[mt][ntl][j] + bz;
            }
        }
    }
}

// ---------------- host ----------------
extern "C" void kernel_launch(void* const* d_in, const int* in_sizes, int n_in,
                              void* d_out, int out_size, void* d_ws, size_t ws_size,
                              hipStream_t stream)
{
    const float* x        = (const float*)d_in[0];
    const float* pre_bias = (const float*)d_in[1];
    const float* W_eh     = (const float*)d_in[2];
    const float* b_eh     = (const float*)d_in[3];
    const float* W_eo     = (const float*)d_in[4];
    const float* b_eo     = (const float*)d_in[5];
    const float* lat_b    = (const float*)d_in[6];
    const float* W_dh     = (const float*)d_in[7];
    const float* b_dh     = (const float*)d_in[8];
    const float* W_do     = (const float*)d_in[9];
    const float* b_do     = (const float*)d_in[10];
    const float* dec_b    = (const float*)d_in[11];

    float* out = (float*)d_out;
    float* recon_out = out;
    float* sl_out    = out + (size_t)B_TOT * 256;
    float* pre_out   = sl_out + (size_t)B_TOT * 64;
    float* mask_out  = pre_out + (size_t)B_TOT * 64;
    float* spars_out = mask_out + (size_t)B_TOT * 64;

    // ws: WdhT 128K | bias3 1K | WdoF 256K | WehHi 256K | WehLo 256K | WeoHi 64K | WeoLo 64K
    //     | fcount 64B | flist 512K | t5v B*20 | t5i B*20 | hHi B*1024 | hLo B*1024  (~275 MB)
    char* ws = (char*)d_ws;
    float* WdhT           = (float*)ws;
    float* bias3          = (float*)(ws + 131072);
    unsigned short* WdoF  = (unsigned short*)(ws + 132096);
    unsigned short* WehHi = (unsigned short*)(ws + 394240);
    unsigned short* WehLo = (unsigned short*)(ws + 656384);
    unsigned short* WeoHi = (unsigned short*)(ws + 918528);
    unsigned short* WeoLo = (unsigned short*)(ws + 984064);
    int* fcount           = (int*)(ws + 1049600);
    int* flist            = (int*)(ws + 1049664);
    float* t5v            = (float*)(ws + 1049664 + 524288);
    int*   t5i            = (int*)  (ws + 1049664 + 524288 + (size_t)B_TOT * 20);
    unsigned short* hHi   = (unsigned short*)(ws + 1049664 + 524288 + (size_t)B_TOT * 40);
    unsigned short* hLo   = hHi + (size_t)B_TOT * 512;

    k_prep<<<32, 256, 0, stream>>>(W_dh, b_do, dec_b, pre_bias, W_do, W_eh, W_eo,
                                   WdhT, bias3, WdoF, WehHi, WehLo, WeoHi, WeoLo,
                                   spars_out, fcount);

    k_enc1<<<B_TOT / 64, 512, 0, stream>>>(x, pre_bias, WehHi, WehLo, b_eh, hHi, hLo);

    k_enc2_topk<<<B_TOT / 64, 256, 0, stream>>>(hHi, hLo, WeoHi, WeoLo, b_eo, lat_b,
                                                pre_out, mask_out, sl_out, t5v, t5i,
                                                fcount, flist);

    k_repair<<<256, 256, 0, stream>>>(x, pre_bias, W_eh, b_eh, W_eo, b_eo, lat_b,
                                      fcount, flist, pre_out, mask_out, sl_out,
                                      t5v, t5i);

    k_dec<<<B_TOT / 64, 256, 0, stream>>>(t5v, t5i, WdhT, b_dh, WdoF, bias3, recon_out);
}

// Round 9
// 619.493 us; speedup vs baseline: 1.3876x; 1.0941x over previous
//
#include <hip/hip_runtime.h>
#include <stdint.h>

#define B_TOT 131072
#define GAP_TAU 2.5e-4f

typedef short v8s __attribute__((ext_vector_type(8)));
typedef float v4f __attribute__((ext_vector_type(4)));

__device__ __forceinline__ unsigned short f2bf(float f) {
    union { float f; unsigned u; } v; v.f = f;
    unsigned u = v.u;
    u += 0x7fffu + ((u >> 16) & 1u);      // RNE
    return (unsigned short)(u >> 16);
}
__device__ __forceinline__ float bf2f(unsigned short s) {
    union { unsigned u; float f; } v; v.u = ((unsigned)s) << 16;
    return v.f;
}
__device__ __forceinline__ unsigned pack2(float lo, float hi) {
    return (unsigned)f2bf(lo) | ((unsigned)f2bf(hi) << 16);
}

// ---------------- K0: prep (weights swizzle + fcount zero) ----------------
__global__ void k_prep(const float* __restrict__ W_dh,
                       const float* __restrict__ b_do,
                       const float* __restrict__ dec_b,
                       const float* __restrict__ pre_bias,
                       const float* __restrict__ W_do,
                       const float* __restrict__ W_eh,
                       const float* __restrict__ W_eo,
                       float* __restrict__ WdhT,
                       float* __restrict__ bias3,
                       unsigned short* __restrict__ Wdo_frag,
                       unsigned short* __restrict__ WehHi,
                       unsigned short* __restrict__ WehLo,
                       unsigned short* __restrict__ WeoHi,
                       unsigned short* __restrict__ WeoLo,
                       float* __restrict__ spars_out,
                       int* __restrict__ fcount)
{
    int t = blockIdx.x * blockDim.x + threadIdx.x;
    int nthr = gridDim.x * blockDim.x;
    for (int i = t; i < 512 * 64; i += nthr) {
        int h = i >> 6, l = i & 63;
        WdhT[l * 512 + h] = W_dh[i];
    }
    for (int g = t; g < 16384; g += nthr) {     // Wdo B-frag
        int lane = g & 63;
        int q = g >> 6;
        int nt = q >> 4, kc = q & 15;
        int col = nt * 16 + (lane & 15);
        int kbase = kc * 32 + (lane >> 4) * 8;
        const float* src = &W_do[(size_t)col * 512 + kbase];
        unsigned short* dst = &Wdo_frag[(size_t)g * 8];
        #pragma unroll
        for (int i = 0; i < 8; i++) dst[i] = f2bf(src[i]);
    }
    for (int g = t; g < 32 * 8 * 64; g += nthr) {   // W_eh hi/lo A-frag
        int lane = g & 63;
        int rem = g >> 6;
        int kcg = rem & 7, ct = rem >> 3;
        int c = ct * 16 + (lane & 15);
        int k = kcg * 32 + (lane >> 4) * 8;
        const float* src = &W_eh[(size_t)c * 256 + k];
        #pragma unroll
        for (int i = 0; i < 8; i++) {
            unsigned short hi = f2bf(src[i]);
            WehHi[(size_t)g * 8 + i] = hi;
            WehLo[(size_t)g * 8 + i] = f2bf(src[i] - bf2f(hi));
        }
    }
    for (int g = t; g < 4 * 16 * 64; g += nthr) {   // W_eo hi/lo A-frag
        int lane = g & 63;
        int rem = g >> 6;
        int kcg = rem & 15, lt = rem >> 4;
        int l = lt * 16 + (lane & 15);
        int k = kcg * 32 + (lane >> 4) * 8;
        const float* src = &W_eo[(size_t)l * 512 + k];
        #pragma unroll
        for (int i = 0; i < 8; i++) {
            unsigned short hi = f2bf(src[i]);
            WeoHi[(size_t)g * 8 + i] = hi;
            WeoLo[(size_t)g * 8 + i] = f2bf(src[i] - bf2f(hi));
        }
    }
    if (t < 256) bias3[t] = b_do[t] + dec_b[t] + pre_bias[t];
    if (t == 0) { spars_out[0] = 5.0f / 64.0f; *fcount = 0; }
}

// h planes layout (writer-native, fully coalesced stores):
//   element index H(row,k) = ((rowtile*128 + k/4)*16 + row%16)*4 + k%4
//   rowtile = row/16. Plane size = B*512 elements.

// ---------------- K1: h = relu((x-pb) @ W_eh^T + b_eh), split-bf16 MFMA ----------------
__global__ __launch_bounds__(512, 2)
void k_enc1(const float* __restrict__ x,
            const float* __restrict__ pre_bias,
            const unsigned short* __restrict__ WehHi,
            const unsigned short* __restrict__ WehLo,
            const float* __restrict__ b_eh,
            unsigned short* __restrict__ hHi,   // tiled layout (see above)
            unsigned short* __restrict__ hLo)
{
    __shared__ __align__(16) unsigned short aH[8 * 4 * 64 * 8];  // 32 KB
    __shared__ __align__(16) unsigned short aL[8 * 4 * 64 * 8];  // 32 KB
    const int t    = threadIdx.x;
    const int lane = t & 63;
    const int w    = t >> 6;        // 0..7
    const int rb   = blockIdx.x * 64;

    // ---- stage x (64 r x 256 k) hi/lo into frag layout ----
    #pragma unroll
    for (int i = 0; i < 4; i++) {
        const int f    = t + i * 512;       // 0..2047
        const int srow = f >> 5;            // 0..63
        const int kc   = (f >> 2) & 7;      // 0..7
        const int skq  = f & 3;             // 0..3
        const float* xp = &x[(size_t)(rb + srow) * 256 + kc * 32 + skq * 8];
        const float* pp = &pre_bias[kc * 32 + skq * 8];
        const float4 v0 = *reinterpret_cast<const float4*>(xp);
        const float4 v1 = *reinterpret_cast<const float4*>(xp + 4);
        const float4 p0 = *reinterpret_cast<const float4*>(pp);
        const float4 p1 = *reinterpret_cast<const float4*>(pp + 4);
        float fv[8] = {v0.x - p0.x, v0.y - p0.y, v0.z - p0.z, v0.w - p0.w,
                       v1.x - p1.x, v1.y - p1.y, v1.z - p1.z, v1.w - p1.w};
        unsigned hi2[4], lo2[4];
        #pragma unroll
        for (int q = 0; q < 4; q++) {
            unsigned short h0 = f2bf(fv[q * 2]), h1 = f2bf(fv[q * 2 + 1]);
            hi2[q] = (unsigned)h0 | ((unsigned)h1 << 16);
            lo2[q] = (unsigned)f2bf(fv[q * 2] - bf2f(h0)) | ((unsigned)f2bf(fv[q * 2 + 1] - bf2f(h1)) << 16);
        }
        const int mt = srow >> 4;
        const int ln = skq * 16 + (srow & 15);
        *reinterpret_cast<uint4*>(&aH[((kc * 4 + mt) * 64 + ln) * 8]) = *reinterpret_cast<uint4*>(hi2);
        *reinterpret_cast<uint4*>(&aL[((kc * 4 + mt) * 64 + ln) * 8]) = *reinterpret_cast<uint4*>(lo2);
    }
    __syncthreads();

    v4f acc[4][4];
    #pragma unroll
    for (int i = 0; i < 4; i++)
        #pragma unroll
        for (int j = 0; j < 4; j++) acc[i][j] = (v4f){0.f, 0.f, 0.f, 0.f};

    // ---- barrier-free MFMA loop ----
    #pragma unroll 2
    for (int kc = 0; kc < 8; ++kc) {
        v8s wh[4], wl[4];
        #pragma unroll
        for (int ntl = 0; ntl < 4; ntl++) {
            const int ct = w * 4 + ntl;
            const size_t idx = ((size_t)(ct * 8 + kc) * 64 + lane) * 8;
            wh[ntl] = *reinterpret_cast<const v8s*>(&WehHi[idx]);
            wl[ntl] = *reinterpret_cast<const v8s*>(&WehLo[idx]);
        }
        v8s ah[4], al[4];
        #pragma unroll
        for (int mt = 0; mt < 4; mt++) {
            const int off = ((kc * 4 + mt) * 64 + lane) * 8;
            ah[mt] = *reinterpret_cast<const v8s*>(&aH[off]);
            al[mt] = *reinterpret_cast<const v8s*>(&aL[off]);
        }
        #pragma unroll
        for (int mt = 0; mt < 4; mt++) {
            #pragma unroll
            for (int ntl = 0; ntl < 4; ntl++) {
                acc[mt][ntl] = __builtin_amdgcn_mfma_f32_16x16x32_bf16(wh[ntl], ah[mt], acc[mt][ntl], 0, 0, 0);
                acc[mt][ntl] = __builtin_amdgcn_mfma_f32_16x16x32_bf16(wl[ntl], ah[mt], acc[mt][ntl], 0, 0, 0);
                acc[mt][ntl] = __builtin_amdgcn_mfma_f32_16x16x32_bf16(wh[ntl], al[mt], acc[mt][ntl], 0, 0, 0);
            }
        }
    }
    // ---- epilogue: relu(acc + b_eh) -> tiled h planes (1KB contiguous per wave-store) ----
    const int rt0 = rb >> 4;
    #pragma unroll
    for (int mt = 0; mt < 4; mt++) {
        #pragma unroll
        for (int ntl = 0; ntl < 4; ntl++) {
            const int c = w * 64 + ntl * 16 + (lane >> 4) * 4;
            const float4 be = *reinterpret_cast<const float4*>(&b_eh[c]);
            float h0 = fmaxf(acc[mt][ntl][0] + be.x, 0.f);
            float h1 = fmaxf(acc[mt][ntl][1] + be.y, 0.f);
            float h2 = fmaxf(acc[mt][ntl][2] + be.z, 0.f);
            float h3 = fmaxf(acc[mt][ntl][3] + be.w, 0.f);
            unsigned short s0 = f2bf(h0), s1 = f2bf(h1), s2 = f2bf(h2), s3 = f2bf(h3);
            uint2 phi = { (unsigned)s0 | ((unsigned)s1 << 16), (unsigned)s2 | ((unsigned)s3 << 16) };
            uint2 plo = { (unsigned)f2bf(h0 - bf2f(s0)) | ((unsigned)f2bf(h1 - bf2f(s1)) << 16),
                          (unsigned)f2bf(h2 - bf2f(s2)) | ((unsigned)f2bf(h3 - bf2f(s3)) << 16) };
            const int cg = w * 16 + ntl * 4 + (lane >> 4);
            const size_t base = ((size_t)((rt0 + mt) * 128 + cg) * 16 + (lane & 15)) * 4;
            *reinterpret_cast<uint2*>(&hHi[base]) = phi;
            *reinterpret_cast<uint2*>(&hLo[base]) = plo;
        }
    }
}

// ---------------- K2: pre_act (split-bf16 MFMA); top-5; gap-flag; outputs ----------------
__global__ __launch_bounds__(256, 4)
void k_enc2_topk(const unsigned short* __restrict__ hHi,   // tiled layout
                 const unsigned short* __restrict__ hLo,
                 const unsigned short* __restrict__ WeoHi,
                 const unsigned short* __restrict__ WeoLo,
                 const float* __restrict__ b_eo,
                 const float* __restrict__ lat_b,
                 float* __restrict__ pre_out,
                 float* __restrict__ mask_out,
                 float* __restrict__ sl_out,
                 float* __restrict__ t5v,          // global [B][5]
                 int*   __restrict__ t5i,
                 int*   __restrict__ fcount,
                 int*   __restrict__ flist)
{
    __shared__ float pa[64][68];
    __shared__ unsigned long long mbits[64];
    const int t    = threadIdx.x;
    const int lane = t & 63;
    const int w    = t >> 6;
    const int rb   = blockIdx.x * 64;
    const int rt   = (rb >> 4) + w;     // wave's row tile

    v4f acc[4];
    #pragma unroll
    for (int i = 0; i < 4; i++) acc[i] = (v4f){0.f, 0.f, 0.f, 0.f};

    #pragma unroll 2
    for (int kcl = 0; kcl < 16; ++kcl) {
        const int cg = kcl * 8 + (lane >> 4) * 2;
        const size_t b1 = ((size_t)(rt * 128 + cg) * 16 + (lane & 15)) * 4;
        union { uint4 u; v8s v; } hh, hl;
        {
            const uint2 a0 = *reinterpret_cast<const uint2*>(&hHi[b1]);
            const uint2 a1 = *reinterpret_cast<const uint2*>(&hHi[b1 + 64]);
            hh.u = (uint4){a0.x, a0.y, a1.x, a1.y};
            const uint2 c0 = *reinterpret_cast<const uint2*>(&hLo[b1]);
            const uint2 c1 = *reinterpret_cast<const uint2*>(&hLo[b1 + 64]);
            hl.u = (uint4){c0.x, c0.y, c1.x, c1.y};
        }
        #pragma unroll
        for (int lt = 0; lt < 4; lt++) {
            const size_t idx = ((size_t)(lt * 16 + kcl) * 64 + lane) * 8;
            const v8s wh = *reinterpret_cast<const v8s*>(&WeoHi[idx]);
            const v8s wl = *reinterpret_cast<const v8s*>(&WeoLo[idx]);
            acc[lt] = __builtin_amdgcn_mfma_f32_16x16x32_bf16(wh, hh.v, acc[lt], 0, 0, 0);
            acc[lt] = __builtin_amdgcn_mfma_f32_16x16x32_bf16(wl, hh.v, acc[lt], 0, 0, 0);
            acc[lt] = __builtin_amdgcn_mfma_f32_16x16x32_bf16(wh, hl.v, acc[lt], 0, 0, 0);
        }
    }
    #pragma unroll
    for (int lt = 0; lt < 4; lt++) {
        const int l0 = lt * 16 + ((lane >> 4) << 2);
        const float4 be = *reinterpret_cast<const float4*>(&b_eo[l0]);
        const float4 lb = *reinterpret_cast<const float4*>(&lat_b[l0]);
        float4 o;
        o.x = acc[lt][0] + be.x + lb.x;
        o.y = acc[lt][1] + be.y + lb.y;
        o.z = acc[lt][2] + be.z + lb.z;
        o.w = acc[lt][3] + be.w + lb.w;
        *reinterpret_cast<float4*>(&pa[w * 16 + (lane & 15)][l0]) = o;
    }
    __syncthreads();
    if (t < 64) {
        int r = t;
        unsigned long long used = 0ULL;
        float bv[5]; int bi[5];
        #pragma unroll
        for (int p = 0; p < 5; p++) {
            float best = -3.402823466e38f; int bidx = 0;
            for (int j = 0; j < 64; j++) {
                float v = pa[r][j];
                if (!((used >> j) & 1ULL) && v > best) { best = v; bidx = j; }
            }
            used |= 1ULL << bidx;
            bv[p] = best; bi[p] = bidx;
        }
        mbits[r] = used;
        size_t gr = (size_t)(rb + r);
        #pragma unroll
        for (int p = 0; p < 5; p++) { t5v[gr * 5 + p] = bv[p]; t5i[gr * 5 + p] = bi[p]; }
        float v6 = -3.402823466e38f;
        for (int j = 0; j < 64; j++) {
            float v = pa[r][j];
            if (!((used >> j) & 1ULL) && v > v6) v6 = v;
        }
        if (bv[4] - v6 < GAP_TAU) {
            int slot = atomicAdd(fcount, 1);
            flist[slot] = rb + r;
        }
    }
    __syncthreads();
    {
        int row = t >> 2, c0 = (t & 3) * 16;
        size_t gr = (size_t)(rb + row);
        unsigned long long bits = mbits[row];
        #pragma unroll
        for (int g = 0; g < 4; g++) {
            int c = c0 + g * 4;
            float p0 = pa[row][c + 0], p1 = pa[row][c + 1], p2 = pa[row][c + 2], p3 = pa[row][c + 3];
            float m0 = (float)((bits >> (c + 0)) & 1ULL);
            float m1 = (float)((bits >> (c + 1)) & 1ULL);
            float m2 = (float)((bits >> (c + 2)) & 1ULL);
            float m3 = (float)((bits >> (c + 3)) & 1ULL);
            float4 pv = {p0, p1, p2, p3};
            float4 mv = {m0, m1, m2, m3};
            float4 sv = {m0 * p0, m1 * p1, m2 * p2, m3 * p3};
            *reinterpret_cast<float4*>(&pre_out[gr * 64 + c])  = pv;
            *reinterpret_cast<float4*>(&mask_out[gr * 64 + c]) = mv;
            *reinterpret_cast<float4*>(&sl_out[gr * 64 + c])   = sv;
        }
    }
}

// ---------------- K2b: fp32 exact repair of gap-flagged rows ----------------
__global__ __launch_bounds__(256)
void k_repair(const float* __restrict__ x,
              const float* __restrict__ pre_bias,
              const float* __restrict__ W_eh,     // [512][256]
              const float* __restrict__ b_eh,
              const float* __restrict__ W_eo,     // [64][512]
              const float* __restrict__ b_eo,
              const float* __restrict__ lat_b,
              const int* __restrict__ fcount,
              const int* __restrict__ flist,
              float* __restrict__ pre_out,
              float* __restrict__ mask_out,
              float* __restrict__ sl_out,
              float* __restrict__ t5v,
              int*   __restrict__ t5i)
{
    __shared__ float xs[256];
    __shared__ float hs[512];
    __shared__ float part[64][4];
    __shared__ float pav[64];
    __shared__ unsigned long long bitsS;
    const int t = threadIdx.x;
    const int n = *fcount;
    #pragma unroll 1
    for (int it = blockIdx.x; it < n; it += gridDim.x) {
        const int r = flist[it];
        xs[t] = x[(size_t)r * 256 + t] - pre_bias[t];
        __syncthreads();
        #pragma unroll 1
        for (int j = t; j < 512; j += 256) {
            const float* wr = &W_eh[(size_t)j * 256];
            float acc = 0.f;
            #pragma unroll
            for (int k = 0; k < 256; k += 4) {
                const float4 wv = *reinterpret_cast<const float4*>(&wr[k]);
                acc = fmaf(wv.x, xs[k + 0], acc);
                acc = fmaf(wv.y, xs[k + 1], acc);
                acc = fmaf(wv.z, xs[k + 2], acc);
                acc = fmaf(wv.w, xs[k + 3], acc);
            }
            hs[j] = fmaxf(acc + b_eh[j], 0.f);
        }
        __syncthreads();
        {
            const int l = t & 63, q = t >> 6;
            const float* wr = &W_eo[(size_t)l * 512 + q * 128];
            const float* hp = &hs[q * 128];
            float acc = 0.f;
            #pragma unroll
            for (int k = 0; k < 128; k += 4) {
                const float4 wv = *reinterpret_cast<const float4*>(&wr[k]);
                acc = fmaf(wv.x, hp[k + 0], acc);
                acc = fmaf(wv.y, hp[k + 1], acc);
                acc = fmaf(wv.z, hp[k + 2], acc);
                acc = fmaf(wv.w, hp[k + 3], acc);
            }
            part[l][q] = acc;
        }
        __syncthreads();
        if (t < 64)
            pav[t] = ((part[t][0] + part[t][1]) + (part[t][2] + part[t][3])) + b_eo[t] + lat_b[t];
        __syncthreads();
        if (t == 0) {
            unsigned long long used = 0ULL;
            const size_t gr = (size_t)r;
            #pragma unroll
            for (int p = 0; p < 5; p++) {
                float best = -3.402823466e38f; int bidx = 0;
                for (int j = 0; j < 64; j++) {
                    float v = pav[j];
                    if (!((used >> j) & 1ULL) && v > best) { best = v; bidx = j; }
                }
                used |= 1ULL << bidx;
                t5v[gr * 5 + p] = best; t5i[gr * 5 + p] = bidx;
            }
            bitsS = used;
        }
        __syncthreads();
        if (t < 64) {
            const size_t gr = (size_t)r;
            const float v = pav[t];
            const float m = (float)((bitsS >> t) & 1ULL);
            pre_out[gr * 64 + t]  = v;
            mask_out[gr * 64 + t] = m;
            sl_out[gr * 64 + t]   = m * v;
        }
        __syncthreads();
    }
}

// ---------------- K3 helpers ----------------
__device__ __forceinline__ void hd_build(short* __restrict__ sAbuf,
                                         const float (* __restrict__ svv)[5],
                                         const int (* __restrict__ sii)[5],
                                         const float* __restrict__ WdhT,
                                         const float* __restrict__ b_dh,
                                         int kbase, int r, int w)
{
    float a[32];
    #pragma unroll
    for (int q = 0; q < 8; q++) {
        const float4 bd = *reinterpret_cast<const float4*>(&b_dh[kbase + q * 4]);
        a[q * 4 + 0] = bd.x; a[q * 4 + 1] = bd.y; a[q * 4 + 2] = bd.z; a[q * 4 + 3] = bd.w;
    }
    #pragma unroll
    for (int p = 0; p < 5; p++) {
        const float s = svv[r][p];
        const float4* wp = reinterpret_cast<const float4*>(&WdhT[(size_t)sii[r][p] * 512 + kbase]);
        #pragma unroll
        for (int q = 0; q < 8; q++) {
            const float4 wv = wp[q];
            a[q * 4 + 0] = fmaf(s, wv.x, a[q * 4 + 0]);
            a[q * 4 + 1] = fmaf(s, wv.y, a[q * 4 + 1]);
            a[q * 4 + 2] = fmaf(s, wv.z, a[q * 4 + 2]);
            a[q * 4 + 3] = fmaf(s, wv.w, a[q * 4 + 3]);
        }
    }
    char* base = (char*)sAbuf + r * 272 + w * 64;
    #pragma unroll
    for (int q2 = 0; q2 < 4; q2++) {
        uint4 o;
        o.x = pack2(fmaxf(a[q2 * 8 + 0], 0.f), fmaxf(a[q2 * 8 + 1], 0.f));
        o.y = pack2(fmaxf(a[q2 * 8 + 2], 0.f), fmaxf(a[q2 * 8 + 3], 0.f));
        o.z = pack2(fmaxf(a[q2 * 8 + 4], 0.f), fmaxf(a[q2 * 8 + 5], 0.f));
        o.w = pack2(fmaxf(a[q2 * 8 + 6], 0.f), fmaxf(a[q2 * 8 + 7], 0.f));
        *reinterpret_cast<uint4*>(base + q2 * 16) = o;
    }
}

// ---------------- K3: recon via bf16 MFMA, double-buffered hd build ----------------
__global__ __launch_bounds__(256)
void k_dec(const float* __restrict__ t5v, const int* __restrict__ t5i,
           const float* __restrict__ WdhT,        // [64][512] fp32
           const float* __restrict__ b_dh,
           const unsigned short* __restrict__ Wdo_frag,
           const float* __restrict__ bias3,
           float* __restrict__ recon)             // global [B][256]
{
    __shared__ __align__(16) short sA[2][64 * 136];
    __shared__ float svv[64][5];
    __shared__ int   sii[64][5];
    const int t    = threadIdx.x;
    const int rb   = blockIdx.x * 64;
    const int lane = t & 63;
    const int w    = t >> 6;
    const int r    = t & 63;

    for (int i = t; i < 320; i += 256) {
        int rr = i / 5, p = i % 5;
        size_t lr = (size_t)(rb + rr);
        svv[rr][p] = t5v[lr * 5 + p];
        sii[rr][p] = t5i[lr * 5 + p];
    }
    __syncthreads();

    v4f acc[4][4];
    #pragma unroll
    for (int i = 0; i < 4; i++)
        #pragma unroll
        for (int j = 0; j < 4; j++) acc[i][j] = (v4f){0.f, 0.f, 0.f, 0.f};

    hd_build(sA[0], svv, sii, WdhT, b_dh, w * 32, r, w);
    __syncthreads();

    #pragma unroll 1
    for (int c = 0; c < 4; ++c) {
        // prefetch-build next chunk into the other buffer (overlaps with MFMA below)
        if (c < 3)
            hd_build(sA[(c + 1) & 1], svv, sii, WdhT, b_dh, (c + 1) * 128 + w * 32, r, w);
        const short* sAc = sA[c & 1];
        #pragma unroll
        for (int kcl = 0; kcl < 4; ++kcl) {
            const int kcg = c * 4 + kcl;
            v8s af[4];
            #pragma unroll
            for (int mt = 0; mt < 4; mt++)
                af[mt] = *reinterpret_cast<const v8s*>(
                    (const char*)sAc + (mt * 16 + (lane & 15)) * 272 + kcl * 64 + (lane >> 4) * 16);
            v8s bf[4];
            #pragma unroll
            for (int ntl = 0; ntl < 4; ntl++) {
                const int ntg = w * 4 + ntl;
                bf[ntl] = *reinterpret_cast<const v8s*>(
                    Wdo_frag + ((size_t)(ntg * 16 + kcg) * 64 + lane) * 8);
            }
            #pragma unroll
            for (int mt = 0; mt < 4; mt++)
                #pragma unroll
                for (int ntl = 0; ntl < 4; ntl++)
                    acc[mt][ntl] = __builtin_amdgcn_mfma_f32_16x16x32_bf16(
                        af[mt], bf[ntl], acc[mt][ntl], 0, 0, 0);
        }
        __syncthreads();
    }
    #pragma unroll
    for (int ntl = 0; ntl < 4; ntl++) {
        const int col = w * 64 + ntl * 16 + (lane & 15);
        const float bz = bias3[col];
        #pragma unroll
        for (int mt = 0; mt < 4; mt++) {
            #pragma unroll
            for (int j = 0; j < 4; j++) {
                const size_t row = (size_t)(rb + mt * 16 + (lane >> 4) * 4 + j);
                recon[row * 256 + col] = acc[mt][ntl][j] + bz;
            }
        }
    }
}

// ---------------- host ----------------
extern "C" void kernel_launch(void* const* d_in, const int* in_sizes, int n_in,
                              void* d_out, int out_size, void* d_ws, size_t ws_size,
                              hipStream_t stream)
{
    const float* x        = (const float*)d_in[0];
    const float* pre_bias = (const float*)d_in[1];
    const float* W_eh     = (const float*)d_in[2];
    const float* b_eh     = (const float*)d_in[3];
    const float* W_eo     = (const float*)d_in[4];
    const float* b_eo     = (const float*)d_in[5];
    const float* lat_b    = (const float*)d_in[6];
    const float* W_dh     = (const float*)d_in[7];
    const float* b_dh     = (const float*)d_in[8];
    const float* W_do     = (const float*)d_in[9];
    const float* b_do     = (const float*)d_in[10];
    const float* dec_b    = (const float*)d_in[11];

    float* out = (float*)d_out;
    float* recon_out = out;
    float* sl_out    = out + (size_t)B_TOT * 256;
    float* pre_out   = sl_out + (size_t)B_TOT * 64;
    float* mask_out  = pre_out + (size_t)B_TOT * 64;
    float* spars_out = mask_out + (size_t)B_TOT * 64;

    char* ws = (char*)d_ws;
    float* WdhT           = (float*)ws;
    float* bias3          = (float*)(ws + 131072);
    unsigned short* WdoF  = (unsigned short*)(ws + 132096);
    unsigned short* WehHi = (unsigned short*)(ws + 394240);
    unsigned short* WehLo = (unsigned short*)(ws + 656384);
    unsigned short* WeoHi = (unsigned short*)(ws + 918528);
    unsigned short* WeoLo = (unsigned short*)(ws + 984064);
    int* fcount           = (int*)(ws + 1049600);
    int* flist            = (int*)(ws + 1049664);
    float* t5v            = (float*)(ws + 1049664 + 524288);
    int*   t5i            = (int*)  (ws + 1049664 + 524288 + (size_t)B_TOT * 20);
    unsigned short* hHi   = (unsigned short*)(ws + 1049664 + 524288 + (size_t)B_TOT * 40);
    unsigned short* hLo   = hHi + (size_t)B_TOT * 512;

    k_prep<<<32, 256, 0, stream>>>(W_dh, b_do, dec_b, pre_bias, W_do, W_eh, W_eo,
                                   WdhT, bias3, WdoF, WehHi, WehLo, WeoHi, WeoLo,
                                   spars_out, fcount);

    k_enc1<<<B_TOT / 64, 512, 0, stream>>>(x, pre_bias, WehHi, WehLo, b_eh, hHi, hLo);

    k_enc2_topk<<<B_TOT / 64, 256, 0, stream>>>(hHi, hLo, WeoHi, WeoLo, b_eo, lat_b,
                                                pre_out, mask_out, sl_out, t5v, t5i,
                                                fcount, flist);

    k_repair<<<256, 256, 0, stream>>>(x, pre_bias, W_eh, b_eh, W_eo, b_eo, lat_b,
                                      fcount, flist, pre_out, mask_out, sl_out,
                                      t5v, t5i);

    k_dec<<<B_TOT / 64, 256, 0, stream>>>(t5v, t5i, WdhT, b_dh, WdoF, bias3, recon_out);
}